// Round 2
// baseline (333.339 us; speedup 1.0000x reference)
//
#include <hip/hip_runtime.h>
#include <hip/hip_bf16.h>

#define T_SEQ 512
#define NH 8
#define DEPTH 64
#define UNITS_ 512
#define SCALE2 2.8853900817779268f   // 2*log2(e)
#define LOG2E 1.4426950408889634f

typedef __attribute__((ext_vector_type(8))) short short8;
typedef __attribute__((ext_vector_type(4))) float floatx4;

// ================= fused QK projection + per-head transform =================
// 32-row m-tiles -> 512 blocks (2 blocks/CU, 8 waves/CU).
// z=0: C = query@Wq+bq (32x64 tile, n-tile == one head), then
//      eq[b,h,t,e] = exp2(SCALE2 * (C @ Wq_h[h])[t,e])
// z=1: C = key@Wk+bk, then
//      ekT[b,h,e,s] = exp2(SCALE2 * ((C @ Wk_h[h])[s,e] + b_h[h,e]))  (transposed)
//      KhT[b,h,d,s] = bf16(C[s,d])                                    (transposed)
__global__ __launch_bounds__(256) void qk_head_fused(
    const float* __restrict__ query, const float* __restrict__ key,
    const float* __restrict__ Wq, const float* __restrict__ bq,
    const float* __restrict__ Wk, const float* __restrict__ bk,
    const float* __restrict__ Wq_h, const float* __restrict__ Wk_h,
    const float* __restrict__ bh,
    float* __restrict__ eq, float* __restrict__ ekT,
    __hip_bfloat16* __restrict__ KhT)
{
    __shared__ float S1[64][36];   // stage1: rows 0..31 = As [k][m32]; stage2: C^T [d64][s32]
    __shared__ float S2[64][68];   // stage1: rows 0..31 = Bs [k][n64]; stage2: Wh [d][e], then eT scratch

    const int tid = threadIdx.x;
    const int which = blockIdx.z;            // 0 = Q path, 1 = K path
    const int h  = blockIdx.x;               // head (n-tile == head depth); id%8==h -> per-XCD W locality
    const int m0 = blockIdx.y * 32;          // row in [0,1024): b*512 + t
    const int n0 = h * 64;
    const int b  = m0 >> 9;
    const int t0 = m0 & 511;
    const int bh_i = b * NH + h;

    const float* In   = which ? key : query;
    const float* W    = which ? Wk  : Wq;
    const float* bias = which ? bk  : bq;
    const float* Wp   = (which ? Wk_h : Wq_h) + h * 4096;

    const int arow = tid >> 3;          // m 0..31
    const int acol = (tid & 7) * 4;     // k base 0..28
    const int bkk = tid >> 3;           // k 0..31
    const int bn = (tid & 7) * 8;       // n base

    const int ti = tid >> 4;            // 0..15 -> m = 2*ti
    const int tj = tid & 15;            // 0..15 -> n = 4*tj

    // early prefetch of the per-head weight tile (held in regs through main loop)
    const int wrow = tid >> 2;          // d 0..63
    const int wcol = (tid & 3) * 16;    // e base
    float4 wh0 = *(const float4*)&Wp[wrow * 64 + wcol + 0];
    float4 wh1 = *(const float4*)&Wp[wrow * 64 + wcol + 4];
    float4 wh2 = *(const float4*)&Wp[wrow * 64 + wcol + 8];
    float4 wh3 = *(const float4*)&Wp[wrow * 64 + wcol + 12];

    float4 acc0 = make_float4(0.f, 0.f, 0.f, 0.f);
    float4 acc1 = make_float4(0.f, 0.f, 0.f, 0.f);

    // prefetch k-tile 0
    float4 av  = *(const float4*)&In[(m0 + arow) * 512 + acol];
    float4 bv0 = *(const float4*)&W[bkk * 512 + n0 + bn];
    float4 bv1 = *(const float4*)&W[bkk * 512 + n0 + bn + 4];

    for (int k0 = 0; k0 < 512; k0 += 32) {
        __syncthreads();
        S1[acol + 0][arow] = av.x;
        S1[acol + 1][arow] = av.y;
        S1[acol + 2][arow] = av.z;
        S1[acol + 3][arow] = av.w;
        *(float4*)&S2[bkk][bn] = bv0;
        *(float4*)&S2[bkk][bn + 4] = bv1;
        __syncthreads();
        if (k0 + 32 < 512) {   // prefetch next k-tile; latency hides under the fma block
            av  = *(const float4*)&In[(m0 + arow) * 512 + k0 + 32 + acol];
            bv0 = *(const float4*)&W[(k0 + 32 + bkk) * 512 + n0 + bn];
            bv1 = *(const float4*)&W[(k0 + 32 + bkk) * 512 + n0 + bn + 4];
        }
        #pragma unroll
        for (int kk = 0; kk < 32; ++kk) {
            float2 a2 = *(const float2*)&S1[kk][2 * ti];
            float4 b4 = *(const float4*)&S2[kk][4 * tj];
            acc0.x = fmaf(a2.x, b4.x, acc0.x);
            acc0.y = fmaf(a2.x, b4.y, acc0.y);
            acc0.z = fmaf(a2.x, b4.z, acc0.z);
            acc0.w = fmaf(a2.x, b4.w, acc0.w);
            acc1.x = fmaf(a2.y, b4.x, acc1.x);
            acc1.y = fmaf(a2.y, b4.y, acc1.y);
            acc1.z = fmaf(a2.y, b4.z, acc1.z);
            acc1.w = fmaf(a2.y, b4.w, acc1.w);
        }
    }

    // ---- stage 2: per-head 32x64 @ 64x64 transform ----
    float4 bb = *(const float4*)&bias[n0 + 4 * tj];
    __syncthreads();   // all waves done reading S1/S2
    // C^T (+bias) into S1: S1[n_local][m_local]
    *(float2*)&S1[4 * tj + 0][2 * ti] = make_float2(acc0.x + bb.x, acc1.x + bb.x);
    *(float2*)&S1[4 * tj + 1][2 * ti] = make_float2(acc0.y + bb.y, acc1.y + bb.y);
    *(float2*)&S1[4 * tj + 2][2 * ti] = make_float2(acc0.z + bb.z, acc1.z + bb.z);
    *(float2*)&S1[4 * tj + 3][2 * ti] = make_float2(acc0.w + bb.w, acc1.w + bb.w);
    // Wh into S2 [d][e] from the early-prefetched registers
    *(float4*)&S2[wrow][wcol + 0]  = wh0;
    *(float4*)&S2[wrow][wcol + 4]  = wh1;
    *(float4*)&S2[wrow][wcol + 8]  = wh2;
    *(float4*)&S2[wrow][wcol + 12] = wh3;
    __syncthreads();

    float4 qa0 = make_float4(0.f, 0.f, 0.f, 0.f);
    float4 qa1 = make_float4(0.f, 0.f, 0.f, 0.f);
    #pragma unroll 16
    for (int d = 0; d < 64; ++d) {
        float2 a2 = *(const float2*)&S1[d][2 * ti];
        float4 b4 = *(const float4*)&S2[d][4 * tj];
        qa0.x = fmaf(a2.x, b4.x, qa0.x);
        qa0.y = fmaf(a2.x, b4.y, qa0.y);
        qa0.z = fmaf(a2.x, b4.z, qa0.z);
        qa0.w = fmaf(a2.x, b4.w, qa0.w);
        qa1.x = fmaf(a2.y, b4.x, qa1.x);
        qa1.y = fmaf(a2.y, b4.y, qa1.y);
        qa1.z = fmaf(a2.y, b4.z, qa1.z);
        qa1.w = fmaf(a2.y, b4.w, qa1.w);
    }

    if (which == 0) {
        float* outp = eq + ((size_t)bh_i * 512 + t0) * 64;
        float4 o0, o1;
        o0.x = __builtin_amdgcn_exp2f(SCALE2 * qa0.x);
        o0.y = __builtin_amdgcn_exp2f(SCALE2 * qa0.y);
        o0.z = __builtin_amdgcn_exp2f(SCALE2 * qa0.z);
        o0.w = __builtin_amdgcn_exp2f(SCALE2 * qa0.w);
        o1.x = __builtin_amdgcn_exp2f(SCALE2 * qa1.x);
        o1.y = __builtin_amdgcn_exp2f(SCALE2 * qa1.y);
        o1.z = __builtin_amdgcn_exp2f(SCALE2 * qa1.z);
        o1.w = __builtin_amdgcn_exp2f(SCALE2 * qa1.w);
        *(float4*)&outp[(2 * ti + 0) * 64 + 4 * tj] = o0;
        *(float4*)&outp[(2 * ti + 1) * 64 + 4 * tj] = o1;
        return;
    }

    // which == 1: ekT (transposed, exp2'd, +b_h) and KhT (bf16 of C^T)
    float4 bhv = *(const float4*)&bh[h * 64 + 4 * tj];
    __syncthreads();   // all waves done reading S2 as Wh
    *(float2*)&S2[4 * tj + 0][2 * ti] = make_float2(
        __builtin_amdgcn_exp2f(SCALE2 * (qa0.x + bhv.x)),
        __builtin_amdgcn_exp2f(SCALE2 * (qa1.x + bhv.x)));
    *(float2*)&S2[4 * tj + 1][2 * ti] = make_float2(
        __builtin_amdgcn_exp2f(SCALE2 * (qa0.y + bhv.y)),
        __builtin_amdgcn_exp2f(SCALE2 * (qa1.y + bhv.y)));
    *(float2*)&S2[4 * tj + 2][2 * ti] = make_float2(
        __builtin_amdgcn_exp2f(SCALE2 * (qa0.z + bhv.z)),
        __builtin_amdgcn_exp2f(SCALE2 * (qa1.z + bhv.z)));
    *(float2*)&S2[4 * tj + 3][2 * ti] = make_float2(
        __builtin_amdgcn_exp2f(SCALE2 * (qa0.w + bhv.w)),
        __builtin_amdgcn_exp2f(SCALE2 * (qa1.w + bhv.w)));
    __syncthreads();

    const int dd = tid >> 2;            // e (or d) 0..63
    const int sc = (tid & 3) * 8;       // s chunk 0,8,16,24
    float* ekp = ekT + ((size_t)bh_i * 64 + dd) * 512 + t0 + sc;
    *(float4*)&ekp[0] = *(float4*)&S2[dd][sc];
    *(float4*)&ekp[4] = *(float4*)&S2[dd][sc + 4];

    // KhT bf16 from S1 (= projected-K^T + bias, untouched by the transpose scratch)
    __hip_bfloat16* kp = KhT + ((size_t)bh_i * 64 + dd) * 512 + t0 + sc;
    union { short8 v; short s[8]; } pk;
    #pragma unroll
    for (int i = 0; i < 8; ++i) {
        __hip_bfloat16 b0 = __hip_bfloat16(S1[dd][sc + i]);
        pk.s[i] = *(short*)&b0;
    }
    *(short8*)kp = pk.v;
}

// ============ additive-attention core (register score + MFMA P@K) ============
// t-tile 8 -> 1024 blocks x 8 waves = full machine wave capacity (4 blocks/CU).
// XCD swizzle: 128 consecutive logical blocks (= 2 full (b,h) groups) per XCD
// so each XCD's L2 keeps its ekT/KhT slices hot.
__global__ __launch_bounds__(512, 8) void attn_v3(
    const float* __restrict__ eq, const float* __restrict__ ekT,
    const __hip_bfloat16* __restrict__ KhT, const float* __restrict__ va_h,
    float* __restrict__ merged)
{
    __shared__ __hip_bfloat16 pA[16][520];   // rows 0..7 = p (bf16); rows 8..15 zeroed
    __shared__ float wsum[8][8];

    const int tid = threadIdx.x;
    const int w = tid >> 6;
    const int l = tid & 63;
    const int bid = blockIdx.x;
    const int swz = (bid & 7) * 128 + (bid >> 3);   // bijective: 1024 % 8 == 0
    const int t0 = (swz & 63) * 8;
    const int bh_i = swz >> 6;          // 0..15 = b*8 + h
    const int h = bh_i & 7;
    const int b = bh_i >> 3;

    // zero the pad rows once (MFMA A-frag reads rows 8..15; outputs discarded)
    {
        short8 z = {0, 0, 0, 0, 0, 0, 0, 0};
        *(short8*)&pA[8 + (tid >> 6)][(tid & 63) * 8] = z;
    }

    const float* eq_p = eq + ((size_t)bh_i * 512 + t0) * 64;
    const float* ekT_p = ekT + (size_t)bh_i * 64 * 512 + tid;   // this thread's s
    const float* va_p = va_h + h * 64;

    float acc[8];
    #pragma unroll
    for (int t = 0; t < 8; ++t) acc[t] = 0.f;

    #pragma unroll
    for (int e0 = 0; e0 < 64; e0 += 16) {
        float ekv[16];
        #pragma unroll
        for (int j = 0; j < 16; ++j) ekv[j] = ekT_p[(e0 + j) * 512];
        float nv[16];
        #pragma unroll
        for (int j = 0; j < 16; ++j) nv[j] = -2.0f * va_p[e0 + j];
        #pragma unroll
        for (int t = 0; t < 8; ++t) {
            float a = acc[t];
            #pragma unroll
            for (int q = 0; q < 4; ++q) {
                float4 e4 = *(const float4*)&eq_p[t * 64 + e0 + q * 4];  // uniform -> s_load
                a = fmaf(nv[q * 4 + 0], __builtin_amdgcn_rcpf(fmaf(e4.x, ekv[q * 4 + 0], 1.0f)), a);
                a = fmaf(nv[q * 4 + 1], __builtin_amdgcn_rcpf(fmaf(e4.y, ekv[q * 4 + 1], 1.0f)), a);
                a = fmaf(nv[q * 4 + 2], __builtin_amdgcn_rcpf(fmaf(e4.z, ekv[q * 4 + 2], 1.0f)), a);
                a = fmaf(nv[q * 4 + 3], __builtin_amdgcn_rcpf(fmaf(e4.w, ekv[q * 4 + 3], 1.0f)), a);
            }
            acc[t] = a;
        }
    }

    // exp (no max-subtract; bounded) + per-t sum across 512 threads
    float ev[8];
    #pragma unroll
    for (int t = 0; t < 8; ++t) {
        float s = __builtin_amdgcn_exp2f(acc[t] * LOG2E);
        ev[t] = s;
        #pragma unroll
        for (int off = 32; off > 0; off >>= 1) s += __shfl_xor(s, off, 64);
        if (l == 0) wsum[t][w] = s;
    }
    __syncthreads();
    #pragma unroll
    for (int t = 0; t < 8; ++t) {
        float4 s0 = *(float4*)&wsum[t][0];
        float4 s1 = *(float4*)&wsum[t][4];
        float inv = 1.0f / (((s0.x + s0.y) + (s0.z + s0.w)) + ((s1.x + s1.y) + (s1.z + s1.w)));
        pA[t][tid] = __hip_bfloat16(ev[t] * inv);   // normalized p, bf16
    }
    __syncthreads();

    // P (8x512) @ K (512x64): 4 waves, wave w owns d-range [16w,16w+16)
    if (w < 4) {
        const __hip_bfloat16* kp = KhT + (size_t)bh_i * 64 * 512
                                   + ((size_t)(w * 16 + (l & 15))) * 512 + (l >> 4) * 8;
        const __hip_bfloat16* ap = &pA[l & 15][(l >> 4) * 8];
        floatx4 oacc = {0.f, 0.f, 0.f, 0.f};
        #pragma unroll
        for (int kt = 0; kt < 16; ++kt) {
            short8 af = *(const short8*)(ap + kt * 32);
            short8 bf = *(const short8*)(kp + kt * 32);
            oacc = __builtin_amdgcn_mfma_f32_16x16x32_bf16(af, bf, oacc, 0, 0, 0);
        }
        if ((l >> 4) < 2) {                  // only C rows 0..7 are valid P rows
            const int row = (l >> 4) * 4;    // t_local base
            const int col = w * 16 + (l & 15);   // d
            float* mp = merged + ((size_t)(b * 512 + t0 + row)) * 512 + h * 64 + col;
            #pragma unroll
            for (int r = 0; r < 4; ++r) mp[r * 512] = oacc[r];
        }
    }
}

// ================= output projection: C = A@Wo + bo =================
// 32x32 tiles -> 512 blocks (2 blocks/CU, 8 waves/CU), 2x2/thread, reg prefetch.
__global__ __launch_bounds__(256) void gemm_out(
    const float* __restrict__ A, const float* __restrict__ W,
    const float* __restrict__ bias, float* __restrict__ C)
{
    __shared__ float As[32][36];   // [k][m]
    __shared__ float Bs[32][36];   // [k][n]

    const int tid = threadIdx.x;
    const int n0 = blockIdx.x * 32;
    const int m0 = blockIdx.y * 32;

    const int arow = tid >> 3;          // m 0..31
    const int acol = (tid & 7) * 4;     // k base 0..28
    const int bkk = tid >> 3;           // k 0..31
    const int bn = (tid & 7) * 4;       // n base 0..28

    const int ti = tid >> 4;            // m = 2*ti
    const int tj = tid & 15;            // n = 2*tj

    float2 acc0 = make_float2(0.f, 0.f);
    float2 acc1 = make_float2(0.f, 0.f);

    float4 av = *(const float4*)&A[(m0 + arow) * 512 + acol];
    float4 bv = *(const float4*)&W[bkk * 512 + n0 + bn];

    for (int k0 = 0; k0 < 512; k0 += 32) {
        __syncthreads();
        As[acol + 0][arow] = av.x;
        As[acol + 1][arow] = av.y;
        As[acol + 2][arow] = av.z;
        As[acol + 3][arow] = av.w;
        *(float4*)&Bs[bkk][bn] = bv;
        __syncthreads();
        if (k0 + 32 < 512) {
            av = *(const float4*)&A[(m0 + arow) * 512 + k0 + 32 + acol];
            bv = *(const float4*)&W[(k0 + 32 + bkk) * 512 + n0 + bn];
        }
        #pragma unroll
        for (int kk = 0; kk < 32; ++kk) {
            float2 a2 = *(const float2*)&As[kk][2 * ti];
            float2 b2 = *(const float2*)&Bs[kk][2 * tj];
            acc0.x = fmaf(a2.x, b2.x, acc0.x);
            acc0.y = fmaf(a2.x, b2.y, acc0.y);
            acc1.x = fmaf(a2.y, b2.x, acc1.x);
            acc1.y = fmaf(a2.y, b2.y, acc1.y);
        }
    }
    float2 bb = *(const float2*)&bias[n0 + 2 * tj];
    float2 o0 = make_float2(acc0.x + bb.x, acc0.y + bb.y);
    float2 o1 = make_float2(acc1.x + bb.x, acc1.y + bb.y);
    *(float2*)&C[(m0 + 2 * ti + 0) * 512 + n0 + 2 * tj] = o0;
    *(float2*)&C[(m0 + 2 * ti + 1) * 512 + n0 + 2 * tj] = o1;
}

extern "C" void kernel_launch(void* const* d_in, const int* in_sizes, int n_in,
                              void* d_out, int out_size, void* d_ws, size_t ws_size,
                              hipStream_t stream) {
    (void)in_sizes; (void)n_in; (void)out_size; (void)ws_size;
    const float* query = (const float*)d_in[0];
    const float* key   = (const float*)d_in[1];
    // d_in[2] (value), d_in[7] (Wv), d_in[8] (bv): dead in the reference
    const float* Wq   = (const float*)d_in[3];
    const float* bq   = (const float*)d_in[4];
    const float* Wk   = (const float*)d_in[5];
    const float* bk   = (const float*)d_in[6];
    const float* Wq_h = (const float*)d_in[9];
    const float* Wk_h = (const float*)d_in[10];
    const float* va_h = (const float*)d_in[11];
    const float* b_h  = (const float*)d_in[12];
    const float* Wo   = (const float*)d_in[13];
    const float* bo   = (const float*)d_in[14];

    float* out = (float*)d_out;
    float* ws = (float*)d_ws;
    const int SZ = 1024 * 512;        // 524288 floats
    float* eqb     = ws;
    float* ekTb    = eqb + SZ;
    float* mergedb = ekTb + SZ;
    __hip_bfloat16* KhTb = (__hip_bfloat16*)(mergedb + SZ);   // 524288 bf16

    // fused: {Q,K} = In@W+b, then per-head transform -> eq / ekT / KhT
    qk_head_fused<<<dim3(8, 32, 2), 256, 0, stream>>>(query, key, Wq, bq, Wk, bk,
                                                      Wq_h, Wk_h, b_h,
                                                      eqb, ekTb, KhTb);
    // scores -> softmax -> P@K (MFMA); 1024 blocks, XCD-swizzled
    attn_v3<<<dim3(1024, 1, 1), 512, 0, stream>>>(eqb, ekTb, KhTb, va_h, mergedb);
    // out = merged@Wo + bo  (512 blocks)
    gemm_out<<<dim3(16, 32, 1), 256, 0, stream>>>(mergedb, Wo, bo, out);
}

// Round 3
// 188.300 us; speedup vs baseline: 1.7703x; 1.7703x over previous
//
#include <hip/hip_runtime.h>
#include <hip/hip_bf16.h>

#define T_SEQ 512
#define NH 8
#define DEPTH 64
#define UNITS_ 512
#define SCALE2 2.8853900817779268f   // 2*log2(e)
#define LOG2E 1.4426950408889634f

typedef __attribute__((ext_vector_type(8))) short short8;
typedef __attribute__((ext_vector_type(4))) float floatx4;

// ================= fused QK projection + per-head transform =================
// 32-row m-tiles -> 512 blocks (2 blocks/CU, 8 waves/CU).
// z=0: C = query@Wq+bq (32x64 tile, n-tile == one head), then
//      eq[b,h,t,e] = exp2(SCALE2 * (C @ Wq_h[h])[t,e])
// z=1: C = key@Wk+bk, then
//      ekT[b,h,e,s] = exp2(SCALE2 * ((C @ Wk_h[h])[s,e] + b_h[h,e]))  (transposed)
//      KhT[b,h,d,s] = bf16(C[s,d])                                    (transposed)
__global__ __launch_bounds__(256) void qk_head_fused(
    const float* __restrict__ query, const float* __restrict__ key,
    const float* __restrict__ Wq, const float* __restrict__ bq,
    const float* __restrict__ Wk, const float* __restrict__ bk,
    const float* __restrict__ Wq_h, const float* __restrict__ Wk_h,
    const float* __restrict__ bh,
    float* __restrict__ eq, float* __restrict__ ekT,
    __hip_bfloat16* __restrict__ KhT)
{
    __shared__ float S1[64][36];   // stage1: rows 0..31 = As [k][m32]; stage2: C^T [d64][s32]
    __shared__ float S2[64][68];   // stage1: rows 0..31 = Bs [k][n64]; stage2: Wh [d][e], then eT scratch

    const int tid = threadIdx.x;
    const int which = blockIdx.z;            // 0 = Q path, 1 = K path
    const int h  = blockIdx.x;               // head (n-tile == head depth); id%8==h -> per-XCD W locality
    const int m0 = blockIdx.y * 32;          // row in [0,1024): b*512 + t
    const int n0 = h * 64;
    const int b  = m0 >> 9;
    const int t0 = m0 & 511;
    const int bh_i = b * NH + h;

    const float* In   = which ? key : query;
    const float* W    = which ? Wk  : Wq;
    const float* bias = which ? bk  : bq;
    const float* Wp   = (which ? Wk_h : Wq_h) + h * 4096;

    const int arow = tid >> 3;          // m 0..31
    const int acol = (tid & 7) * 4;     // k base 0..28
    const int bkk = tid >> 3;           // k 0..31
    const int bn = (tid & 7) * 8;       // n base

    const int ti = tid >> 4;            // 0..15 -> m = 2*ti
    const int tj = tid & 15;            // 0..15 -> n = 4*tj

    // early prefetch of the per-head weight tile (held in regs through main loop)
    const int wrow = tid >> 2;          // d 0..63
    const int wcol = (tid & 3) * 16;    // e base
    float4 wh0 = *(const float4*)&Wp[wrow * 64 + wcol + 0];
    float4 wh1 = *(const float4*)&Wp[wrow * 64 + wcol + 4];
    float4 wh2 = *(const float4*)&Wp[wrow * 64 + wcol + 8];
    float4 wh3 = *(const float4*)&Wp[wrow * 64 + wcol + 12];

    float4 acc0 = make_float4(0.f, 0.f, 0.f, 0.f);
    float4 acc1 = make_float4(0.f, 0.f, 0.f, 0.f);

    // prefetch k-tile 0
    float4 av  = *(const float4*)&In[(m0 + arow) * 512 + acol];
    float4 bv0 = *(const float4*)&W[bkk * 512 + n0 + bn];
    float4 bv1 = *(const float4*)&W[bkk * 512 + n0 + bn + 4];

    for (int k0 = 0; k0 < 512; k0 += 32) {
        __syncthreads();
        S1[acol + 0][arow] = av.x;
        S1[acol + 1][arow] = av.y;
        S1[acol + 2][arow] = av.z;
        S1[acol + 3][arow] = av.w;
        *(float4*)&S2[bkk][bn] = bv0;
        *(float4*)&S2[bkk][bn + 4] = bv1;
        __syncthreads();
        if (k0 + 32 < 512) {   // prefetch next k-tile; latency hides under the fma block
            av  = *(const float4*)&In[(m0 + arow) * 512 + k0 + 32 + acol];
            bv0 = *(const float4*)&W[(k0 + 32 + bkk) * 512 + n0 + bn];
            bv1 = *(const float4*)&W[(k0 + 32 + bkk) * 512 + n0 + bn + 4];
        }
        #pragma unroll
        for (int kk = 0; kk < 32; ++kk) {
            float2 a2 = *(const float2*)&S1[kk][2 * ti];
            float4 b4 = *(const float4*)&S2[kk][4 * tj];
            acc0.x = fmaf(a2.x, b4.x, acc0.x);
            acc0.y = fmaf(a2.x, b4.y, acc0.y);
            acc0.z = fmaf(a2.x, b4.z, acc0.z);
            acc0.w = fmaf(a2.x, b4.w, acc0.w);
            acc1.x = fmaf(a2.y, b4.x, acc1.x);
            acc1.y = fmaf(a2.y, b4.y, acc1.y);
            acc1.z = fmaf(a2.y, b4.z, acc1.z);
            acc1.w = fmaf(a2.y, b4.w, acc1.w);
        }
    }

    // ---- stage 2: per-head 32x64 @ 64x64 transform ----
    float4 bb = *(const float4*)&bias[n0 + 4 * tj];
    __syncthreads();   // all waves done reading S1/S2
    // C^T (+bias) into S1: S1[n_local][m_local]
    *(float2*)&S1[4 * tj + 0][2 * ti] = make_float2(acc0.x + bb.x, acc1.x + bb.x);
    *(float2*)&S1[4 * tj + 1][2 * ti] = make_float2(acc0.y + bb.y, acc1.y + bb.y);
    *(float2*)&S1[4 * tj + 2][2 * ti] = make_float2(acc0.z + bb.z, acc1.z + bb.z);
    *(float2*)&S1[4 * tj + 3][2 * ti] = make_float2(acc0.w + bb.w, acc1.w + bb.w);
    // Wh into S2 [d][e] from the early-prefetched registers
    *(float4*)&S2[wrow][wcol + 0]  = wh0;
    *(float4*)&S2[wrow][wcol + 4]  = wh1;
    *(float4*)&S2[wrow][wcol + 8]  = wh2;
    *(float4*)&S2[wrow][wcol + 12] = wh3;
    __syncthreads();

    float4 qa0 = make_float4(0.f, 0.f, 0.f, 0.f);
    float4 qa1 = make_float4(0.f, 0.f, 0.f, 0.f);
    #pragma unroll 16
    for (int d = 0; d < 64; ++d) {
        float2 a2 = *(const float2*)&S1[d][2 * ti];
        float4 b4 = *(const float4*)&S2[d][4 * tj];
        qa0.x = fmaf(a2.x, b4.x, qa0.x);
        qa0.y = fmaf(a2.x, b4.y, qa0.y);
        qa0.z = fmaf(a2.x, b4.z, qa0.z);
        qa0.w = fmaf(a2.x, b4.w, qa0.w);
        qa1.x = fmaf(a2.y, b4.x, qa1.x);
        qa1.y = fmaf(a2.y, b4.y, qa1.y);
        qa1.z = fmaf(a2.y, b4.z, qa1.z);
        qa1.w = fmaf(a2.y, b4.w, qa1.w);
    }

    if (which == 0) {
        float* outp = eq + ((size_t)bh_i * 512 + t0) * 64;
        float4 o0, o1;
        o0.x = __builtin_amdgcn_exp2f(SCALE2 * qa0.x);
        o0.y = __builtin_amdgcn_exp2f(SCALE2 * qa0.y);
        o0.z = __builtin_amdgcn_exp2f(SCALE2 * qa0.z);
        o0.w = __builtin_amdgcn_exp2f(SCALE2 * qa0.w);
        o1.x = __builtin_amdgcn_exp2f(SCALE2 * qa1.x);
        o1.y = __builtin_amdgcn_exp2f(SCALE2 * qa1.y);
        o1.z = __builtin_amdgcn_exp2f(SCALE2 * qa1.z);
        o1.w = __builtin_amdgcn_exp2f(SCALE2 * qa1.w);
        *(float4*)&outp[(2 * ti + 0) * 64 + 4 * tj] = o0;
        *(float4*)&outp[(2 * ti + 1) * 64 + 4 * tj] = o1;
        return;
    }

    // which == 1: ekT (transposed, exp2'd, +b_h) and KhT (bf16 of C^T)
    float4 bhv = *(const float4*)&bh[h * 64 + 4 * tj];
    __syncthreads();   // all waves done reading S2 as Wh
    *(float2*)&S2[4 * tj + 0][2 * ti] = make_float2(
        __builtin_amdgcn_exp2f(SCALE2 * (qa0.x + bhv.x)),
        __builtin_amdgcn_exp2f(SCALE2 * (qa1.x + bhv.x)));
    *(float2*)&S2[4 * tj + 1][2 * ti] = make_float2(
        __builtin_amdgcn_exp2f(SCALE2 * (qa0.y + bhv.y)),
        __builtin_amdgcn_exp2f(SCALE2 * (qa1.y + bhv.y)));
    *(float2*)&S2[4 * tj + 2][2 * ti] = make_float2(
        __builtin_amdgcn_exp2f(SCALE2 * (qa0.z + bhv.z)),
        __builtin_amdgcn_exp2f(SCALE2 * (qa1.z + bhv.z)));
    *(float2*)&S2[4 * tj + 3][2 * ti] = make_float2(
        __builtin_amdgcn_exp2f(SCALE2 * (qa0.w + bhv.w)),
        __builtin_amdgcn_exp2f(SCALE2 * (qa1.w + bhv.w)));
    __syncthreads();

    const int dd = tid >> 2;            // e (or d) 0..63
    const int sc = (tid & 3) * 8;       // s chunk 0,8,16,24
    float* ekp = ekT + ((size_t)bh_i * 64 + dd) * 512 + t0 + sc;
    *(float4*)&ekp[0] = *(float4*)&S2[dd][sc];
    *(float4*)&ekp[4] = *(float4*)&S2[dd][sc + 4];

    // KhT bf16 from S1 (= projected-K^T + bias, untouched by the transpose scratch)
    __hip_bfloat16* kp = KhT + ((size_t)bh_i * 64 + dd) * 512 + t0 + sc;
    union { short8 v; short s[8]; } pk;
    #pragma unroll
    for (int i = 0; i < 8; ++i) {
        __hip_bfloat16 b0 = __hip_bfloat16(S1[dd][sc + i]);
        pk.s[i] = *(short*)&b0;
    }
    *(short8*)kp = pk.v;
}

// ============ additive-attention core (register score + MFMA P@K) ============
// t-tile 8 -> 1024 blocks x 8 waves (4 blocks/CU when VGPR<=64).
// launch_bounds(512,4): the (512,8) variant capped VGPR at 32 -> scratch spill
// (190 MB writes/dispatch). (512,4) compiles this pattern to 64 VGPR, no spill,
// and 64 VGPR still physically admits 8 waves/SIMD.
// XCD swizzle: bijective, 128 consecutive logical blocks (= 2 (b,h) groups)/XCD.
__global__ __launch_bounds__(512, 4) void attn_v4(
    const float* __restrict__ eq, const float* __restrict__ ekT,
    const __hip_bfloat16* __restrict__ KhT, const float* __restrict__ va_h,
    float* __restrict__ merged)
{
    __shared__ __hip_bfloat16 pA[16][520];   // rows 0..7 = p (bf16); rows 8..15 zeroed
    __shared__ float wsum[8][8];

    const int tid = threadIdx.x;
    const int w = tid >> 6;
    const int l = tid & 63;
    const int bid = blockIdx.x;
    const int swz = (bid & 7) * 128 + (bid >> 3);   // bijective: 1024 % 8 == 0
    const int t0 = (swz & 63) * 8;
    const int bh_i = swz >> 6;          // 0..15 = b*8 + h
    const int h = bh_i & 7;
    const int b = bh_i >> 3;

    // zero the pad rows once (MFMA A-frag reads rows 8..15; outputs discarded)
    {
        short8 z = {0, 0, 0, 0, 0, 0, 0, 0};
        *(short8*)&pA[8 + (tid >> 6)][(tid & 63) * 8] = z;
    }

    const float* eq_p = eq + ((size_t)bh_i * 512 + t0) * 64;
    const float* ekT_p = ekT + (size_t)bh_i * 64 * 512 + tid;   // this thread's s
    const float* va_p = va_h + h * 64;

    float acc[8];
    #pragma unroll
    for (int t = 0; t < 8; ++t) acc[t] = 0.f;

    #pragma unroll
    for (int e0 = 0; e0 < 64; e0 += 16) {
        float ekv[16];
        #pragma unroll
        for (int j = 0; j < 16; ++j) ekv[j] = ekT_p[(e0 + j) * 512];
        float nv[16];
        #pragma unroll
        for (int j = 0; j < 16; ++j) nv[j] = -2.0f * va_p[e0 + j];
        #pragma unroll
        for (int t = 0; t < 8; ++t) {
            float a = acc[t];
            #pragma unroll
            for (int q = 0; q < 4; ++q) {
                float4 e4 = *(const float4*)&eq_p[t * 64 + e0 + q * 4];  // uniform -> s_load
                a = fmaf(nv[q * 4 + 0], __builtin_amdgcn_rcpf(fmaf(e4.x, ekv[q * 4 + 0], 1.0f)), a);
                a = fmaf(nv[q * 4 + 1], __builtin_amdgcn_rcpf(fmaf(e4.y, ekv[q * 4 + 1], 1.0f)), a);
                a = fmaf(nv[q * 4 + 2], __builtin_amdgcn_rcpf(fmaf(e4.z, ekv[q * 4 + 2], 1.0f)), a);
                a = fmaf(nv[q * 4 + 3], __builtin_amdgcn_rcpf(fmaf(e4.w, ekv[q * 4 + 3], 1.0f)), a);
            }
            acc[t] = a;
        }
    }

    // exp (no max-subtract; bounded) + per-t sum across 512 threads
    float ev[8];
    #pragma unroll
    for (int t = 0; t < 8; ++t) {
        float s = __builtin_amdgcn_exp2f(acc[t] * LOG2E);
        ev[t] = s;
        #pragma unroll
        for (int off = 32; off > 0; off >>= 1) s += __shfl_xor(s, off, 64);
        if (l == 0) wsum[t][w] = s;
    }
    __syncthreads();
    #pragma unroll
    for (int t = 0; t < 8; ++t) {
        float4 s0 = *(float4*)&wsum[t][0];
        float4 s1 = *(float4*)&wsum[t][4];
        float inv = 1.0f / (((s0.x + s0.y) + (s0.z + s0.w)) + ((s1.x + s1.y) + (s1.z + s1.w)));
        pA[t][tid] = __hip_bfloat16(ev[t] * inv);   // normalized p, bf16
    }
    __syncthreads();

    // P (8x512) @ K (512x64): 4 waves, wave w owns d-range [16w,16w+16)
    if (w < 4) {
        const __hip_bfloat16* kp = KhT + (size_t)bh_i * 64 * 512
                                   + ((size_t)(w * 16 + (l & 15))) * 512 + (l >> 4) * 8;
        const __hip_bfloat16* ap = &pA[l & 15][(l >> 4) * 8];
        floatx4 oacc = {0.f, 0.f, 0.f, 0.f};
        #pragma unroll
        for (int kt = 0; kt < 16; ++kt) {
            short8 af = *(const short8*)(ap + kt * 32);
            short8 bf = *(const short8*)(kp + kt * 32);
            oacc = __builtin_amdgcn_mfma_f32_16x16x32_bf16(af, bf, oacc, 0, 0, 0);
        }
        if ((l >> 4) < 2) {                  // only C rows 0..7 are valid P rows
            const int row = (l >> 4) * 4;    // t_local base
            const int col = w * 16 + (l & 15);   // d
            float* mp = merged + ((size_t)(b * 512 + t0 + row)) * 512 + h * 64 + col;
            #pragma unroll
            for (int r = 0; r < 4; ++r) mp[r * 512] = oacc[r];
        }
    }
}

// ================= output projection: C = A@Wo + bo =================
// 32x32 tiles -> 512 blocks (2 blocks/CU, 8 waves/CU), 2x2/thread, reg prefetch.
__global__ __launch_bounds__(256) void gemm_out(
    const float* __restrict__ A, const float* __restrict__ W,
    const float* __restrict__ bias, float* __restrict__ C)
{
    __shared__ float As[32][36];   // [k][m]
    __shared__ float Bs[32][36];   // [k][n]

    const int tid = threadIdx.x;
    const int n0 = blockIdx.x * 32;
    const int m0 = blockIdx.y * 32;

    const int arow = tid >> 3;          // m 0..31
    const int acol = (tid & 7) * 4;     // k base 0..28
    const int bkk = tid >> 3;           // k 0..31
    const int bn = (tid & 7) * 4;       // n base 0..28

    const int ti = tid >> 4;            // m = 2*ti
    const int tj = tid & 15;            // n = 2*tj

    float2 acc0 = make_float2(0.f, 0.f);
    float2 acc1 = make_float2(0.f, 0.f);

    float4 av = *(const float4*)&A[(m0 + arow) * 512 + acol];
    float4 bv = *(const float4*)&W[bkk * 512 + n0 + bn];

    for (int k0 = 0; k0 < 512; k0 += 32) {
        __syncthreads();
        As[acol + 0][arow] = av.x;
        As[acol + 1][arow] = av.y;
        As[acol + 2][arow] = av.z;
        As[acol + 3][arow] = av.w;
        *(float4*)&Bs[bkk][bn] = bv;
        __syncthreads();
        if (k0 + 32 < 512) {
            av = *(const float4*)&A[(m0 + arow) * 512 + k0 + 32 + acol];
            bv = *(const float4*)&W[(k0 + 32 + bkk) * 512 + n0 + bn];
        }
        #pragma unroll
        for (int kk = 0; kk < 32; ++kk) {
            float2 a2 = *(const float2*)&As[kk][2 * ti];
            float2 b2 = *(const float2*)&Bs[kk][2 * tj];
            acc0.x = fmaf(a2.x, b2.x, acc0.x);
            acc0.y = fmaf(a2.x, b2.y, acc0.y);
            acc1.x = fmaf(a2.y, b2.x, acc1.x);
            acc1.y = fmaf(a2.y, b2.y, acc1.y);
        }
    }
    float2 bb = *(const float2*)&bias[n0 + 2 * tj];
    float2 o0 = make_float2(acc0.x + bb.x, acc0.y + bb.y);
    float2 o1 = make_float2(acc1.x + bb.x, acc1.y + bb.y);
    *(float2*)&C[(m0 + 2 * ti + 0) * 512 + n0 + 2 * tj] = o0;
    *(float2*)&C[(m0 + 2 * ti + 1) * 512 + n0 + 2 * tj] = o1;
}

extern "C" void kernel_launch(void* const* d_in, const int* in_sizes, int n_in,
                              void* d_out, int out_size, void* d_ws, size_t ws_size,
                              hipStream_t stream) {
    (void)in_sizes; (void)n_in; (void)out_size; (void)ws_size;
    const float* query = (const float*)d_in[0];
    const float* key   = (const float*)d_in[1];
    // d_in[2] (value), d_in[7] (Wv), d_in[8] (bv): dead in the reference
    const float* Wq   = (const float*)d_in[3];
    const float* bq   = (const float*)d_in[4];
    const float* Wk   = (const float*)d_in[5];
    const float* bk   = (const float*)d_in[6];
    const float* Wq_h = (const float*)d_in[9];
    const float* Wk_h = (const float*)d_in[10];
    const float* va_h = (const float*)d_in[11];
    const float* b_h  = (const float*)d_in[12];
    const float* Wo   = (const float*)d_in[13];
    const float* bo   = (const float*)d_in[14];

    float* out = (float*)d_out;
    float* ws = (float*)d_ws;
    const int SZ = 1024 * 512;        // 524288 floats
    float* eqb     = ws;
    float* ekTb    = eqb + SZ;
    float* mergedb = ekTb + SZ;
    __hip_bfloat16* KhTb = (__hip_bfloat16*)(mergedb + SZ);   // 524288 bf16

    // fused: {Q,K} = In@W+b, then per-head transform -> eq / ekT / KhT
    qk_head_fused<<<dim3(8, 32, 2), 256, 0, stream>>>(query, key, Wq, bq, Wk, bk,
                                                      Wq_h, Wk_h, b_h,
                                                      eqb, ekTb, KhTb);
    // scores -> softmax -> P@K (MFMA); 1024 blocks, XCD-swizzled
    attn_v4<<<dim3(1024, 1, 1), 512, 0, stream>>>(eqb, ekTb, KhTb, va_h, mergedb);
    // out = merged@Wo + bo  (512 blocks)
    gemm_out<<<dim3(16, 32, 1), 256, 0, stream>>>(mergedb, Wo, bo, out);
}

// Round 4
// 180.437 us; speedup vs baseline: 1.8474x; 1.0436x over previous
//
#include <hip/hip_runtime.h>
#include <hip/hip_bf16.h>

#define T_SEQ 512
#define NH 8
#define DEPTH 64
#define UNITS_ 512
#define SCALE2 2.8853900817779268f   // 2*log2(e)
#define LOG2E 1.4426950408889634f

typedef __attribute__((ext_vector_type(8))) short short8;
typedef __attribute__((ext_vector_type(4))) float floatx4;

// ================= fused QK projection + per-head transform =================
// R1-measured shape: 64x64 tiles, 256 blocks/path, 4x4 per thread.
__global__ __launch_bounds__(256) void qk_head_fused(
    const float* __restrict__ query, const float* __restrict__ key,
    const float* __restrict__ Wq, const float* __restrict__ bq,
    const float* __restrict__ Wk, const float* __restrict__ bk,
    const float* __restrict__ Wq_h, const float* __restrict__ Wk_h,
    const float* __restrict__ bh,
    float* __restrict__ eq, float* __restrict__ ekT,
    __hip_bfloat16* __restrict__ KhT)
{
    __shared__ float S1[64][68];   // stage1: rows 0..31 = As [k][m]; stage2: C^T [d][s]
    __shared__ float S2[64][68];   // stage1: rows 0..31 = Bs [k][n]; stage2: Wh [d][e], then eT scratch

    const int tid = threadIdx.x;
    const int which = blockIdx.z;            // 0 = Q path, 1 = K path
    const int h  = blockIdx.x;               // head (n-tile == head depth)
    const int m0 = blockIdx.y * 64;          // row in [0,1024): b*512 + t
    const int n0 = h * 64;
    const int b  = m0 >> 9;
    const int t0 = m0 & 511;
    const int bh_i = b * NH + h;

    const float* In   = which ? key : query;
    const float* W    = which ? Wk  : Wq;
    const float* bias = which ? bk  : bq;
    const float* Wp   = (which ? Wk_h : Wq_h) + h * 4096;

    const int arow = tid >> 2;          // m 0..63
    const int acol = (tid & 3) * 8;     // k base 0,8,16,24
    const int bkk = tid >> 3;           // k 0..31
    const int bn = (tid & 7) * 8;       // n base

    const int ti = tid >> 4;            // 0..15
    const int tj = tid & 15;            // 0..15

    // early prefetch of the per-head weight tile (held in regs through main loop)
    const int wrow = tid >> 2;          // d 0..63
    const int wcol = (tid & 3) * 16;    // e base
    float4 wh0 = *(const float4*)&Wp[wrow * 64 + wcol + 0];
    float4 wh1 = *(const float4*)&Wp[wrow * 64 + wcol + 4];
    float4 wh2 = *(const float4*)&Wp[wrow * 64 + wcol + 8];
    float4 wh3 = *(const float4*)&Wp[wrow * 64 + wcol + 12];

    float4 acc[4];
    acc[0] = acc[1] = acc[2] = acc[3] = make_float4(0.f, 0.f, 0.f, 0.f);

    // prefetch k-tile 0
    float4 av0 = *(const float4*)&In[(m0 + arow) * 512 + acol];
    float4 av1 = *(const float4*)&In[(m0 + arow) * 512 + acol + 4];
    float4 bv0 = *(const float4*)&W[bkk * 512 + n0 + bn];
    float4 bv1 = *(const float4*)&W[bkk * 512 + n0 + bn + 4];

    for (int k0 = 0; k0 < 512; k0 += 32) {
        __syncthreads();
        S1[acol + 0][arow] = av0.x;
        S1[acol + 1][arow] = av0.y;
        S1[acol + 2][arow] = av0.z;
        S1[acol + 3][arow] = av0.w;
        S1[acol + 4][arow] = av1.x;
        S1[acol + 5][arow] = av1.y;
        S1[acol + 6][arow] = av1.z;
        S1[acol + 7][arow] = av1.w;
        *(float4*)&S2[bkk][bn] = bv0;
        *(float4*)&S2[bkk][bn + 4] = bv1;
        __syncthreads();
        if (k0 + 32 < 512) {   // prefetch next k-tile; latency hides under the fma block
            av0 = *(const float4*)&In[(m0 + arow) * 512 + k0 + 32 + acol];
            av1 = *(const float4*)&In[(m0 + arow) * 512 + k0 + 32 + acol + 4];
            bv0 = *(const float4*)&W[(k0 + 32 + bkk) * 512 + n0 + bn];
            bv1 = *(const float4*)&W[(k0 + 32 + bkk) * 512 + n0 + bn + 4];
        }
        #pragma unroll
        for (int kk = 0; kk < 32; ++kk) {
            float4 a4 = *(const float4*)&S1[kk][4 * ti];
            float4 b4 = *(const float4*)&S2[kk][4 * tj];
            acc[0].x = fmaf(a4.x, b4.x, acc[0].x);
            acc[0].y = fmaf(a4.x, b4.y, acc[0].y);
            acc[0].z = fmaf(a4.x, b4.z, acc[0].z);
            acc[0].w = fmaf(a4.x, b4.w, acc[0].w);
            acc[1].x = fmaf(a4.y, b4.x, acc[1].x);
            acc[1].y = fmaf(a4.y, b4.y, acc[1].y);
            acc[1].z = fmaf(a4.y, b4.z, acc[1].z);
            acc[1].w = fmaf(a4.y, b4.w, acc[1].w);
            acc[2].x = fmaf(a4.z, b4.x, acc[2].x);
            acc[2].y = fmaf(a4.z, b4.y, acc[2].y);
            acc[2].z = fmaf(a4.z, b4.z, acc[2].z);
            acc[2].w = fmaf(a4.z, b4.w, acc[2].w);
            acc[3].x = fmaf(a4.w, b4.x, acc[3].x);
            acc[3].y = fmaf(a4.w, b4.y, acc[3].y);
            acc[3].z = fmaf(a4.w, b4.z, acc[3].z);
            acc[3].w = fmaf(a4.w, b4.w, acc[3].w);
        }
    }

    // ---- stage 2: per-head 64x64 transform ----
    float4 bb = *(const float4*)&bias[n0 + 4 * tj];
    __syncthreads();   // all waves done reading S1/S2
    // C^T (+bias) into S1: S1[n_local][m_local]
    *(float4*)&S1[4 * tj + 0][4 * ti] =
        make_float4(acc[0].x + bb.x, acc[1].x + bb.x, acc[2].x + bb.x, acc[3].x + bb.x);
    *(float4*)&S1[4 * tj + 1][4 * ti] =
        make_float4(acc[0].y + bb.y, acc[1].y + bb.y, acc[2].y + bb.y, acc[3].y + bb.y);
    *(float4*)&S1[4 * tj + 2][4 * ti] =
        make_float4(acc[0].z + bb.z, acc[1].z + bb.z, acc[2].z + bb.z, acc[3].z + bb.z);
    *(float4*)&S1[4 * tj + 3][4 * ti] =
        make_float4(acc[0].w + bb.w, acc[1].w + bb.w, acc[2].w + bb.w, acc[3].w + bb.w);
    // Wh into S2 [d][e] from the early-prefetched registers
    *(float4*)&S2[wrow][wcol + 0]  = wh0;
    *(float4*)&S2[wrow][wcol + 4]  = wh1;
    *(float4*)&S2[wrow][wcol + 8]  = wh2;
    *(float4*)&S2[wrow][wcol + 12] = wh3;
    __syncthreads();

    float4 qa[4];
    qa[0] = qa[1] = qa[2] = qa[3] = make_float4(0.f, 0.f, 0.f, 0.f);
    #pragma unroll 8
    for (int d = 0; d < 64; ++d) {
        float4 a4 = *(const float4*)&S1[d][4 * ti];
        float4 b4 = *(const float4*)&S2[d][4 * tj];
        qa[0].x = fmaf(a4.x, b4.x, qa[0].x);
        qa[0].y = fmaf(a4.x, b4.y, qa[0].y);
        qa[0].z = fmaf(a4.x, b4.z, qa[0].z);
        qa[0].w = fmaf(a4.x, b4.w, qa[0].w);
        qa[1].x = fmaf(a4.y, b4.x, qa[1].x);
        qa[1].y = fmaf(a4.y, b4.y, qa[1].y);
        qa[1].z = fmaf(a4.y, b4.z, qa[1].z);
        qa[1].w = fmaf(a4.y, b4.w, qa[1].w);
        qa[2].x = fmaf(a4.z, b4.x, qa[2].x);
        qa[2].y = fmaf(a4.z, b4.y, qa[2].y);
        qa[2].z = fmaf(a4.z, b4.z, qa[2].z);
        qa[2].w = fmaf(a4.z, b4.w, qa[2].w);
        qa[3].x = fmaf(a4.w, b4.x, qa[3].x);
        qa[3].y = fmaf(a4.w, b4.y, qa[3].y);
        qa[3].z = fmaf(a4.w, b4.z, qa[3].z);
        qa[3].w = fmaf(a4.w, b4.w, qa[3].w);
    }

    if (which == 0) {
        float* outp = eq + ((size_t)bh_i * 512 + t0) * 64;
        #pragma unroll
        for (int r = 0; r < 4; ++r) {
            float4 o;
            float4 a = qa[r];
            o.x = __builtin_amdgcn_exp2f(SCALE2 * a.x);
            o.y = __builtin_amdgcn_exp2f(SCALE2 * a.y);
            o.z = __builtin_amdgcn_exp2f(SCALE2 * a.z);
            o.w = __builtin_amdgcn_exp2f(SCALE2 * a.w);
            *(float4*)&outp[(4 * ti + r) * 64 + 4 * tj] = o;
        }
        return;
    }

    // which == 1: ekT (transposed, exp2'd, +b_h) and KhT (bf16 of C^T)
    float4 bhv = *(const float4*)&bh[h * 64 + 4 * tj];
    __syncthreads();   // all waves done reading S2 as Wh
    #pragma unroll
    for (int r = 0; r < 4; ++r) {
        S2[4 * tj + 0][4 * ti + r] = __builtin_amdgcn_exp2f(SCALE2 * (qa[r].x + bhv.x));
        S2[4 * tj + 1][4 * ti + r] = __builtin_amdgcn_exp2f(SCALE2 * (qa[r].y + bhv.y));
        S2[4 * tj + 2][4 * ti + r] = __builtin_amdgcn_exp2f(SCALE2 * (qa[r].z + bhv.z));
        S2[4 * tj + 3][4 * ti + r] = __builtin_amdgcn_exp2f(SCALE2 * (qa[r].w + bhv.w));
    }
    __syncthreads();

    const int dd = tid >> 2;
    const int sc = (tid & 3) * 16;
    float* ekp = ekT + ((size_t)bh_i * 64 + dd) * 512 + t0 + sc;
    #pragma unroll
    for (int c = 0; c < 4; ++c)
        *(float4*)&ekp[4 * c] = *(float4*)&S2[dd][sc + 4 * c];

    // KhT bf16 from S1 (= projected-K^T + bias, untouched by the transpose scratch)
    __hip_bfloat16* kp = KhT + ((size_t)bh_i * 64 + dd) * 512 + t0 + sc;
    union { short8 v; short s[8]; } pk0, pk1;
    #pragma unroll
    for (int i = 0; i < 8; ++i) {
        __hip_bfloat16 b0 = __hip_bfloat16(S1[dd][sc + i]);
        __hip_bfloat16 b1 = __hip_bfloat16(S1[dd][sc + 8 + i]);
        pk0.s[i] = *(short*)&b0;
        pk1.s[i] = *(short*)&b1;
    }
    *(short8*)kp = pk0.v;
    *(short8*)(kp + 8) = pk1.v;
}

// ============ additive-attention core (register score + MFMA P@K) ============
// t-tile 16 -> 512 blocks. Full ek column preloaded into 64 VGPRs up front:
// the score loop is then pure register compute (eq/va are wave-uniform ->
// SGPR operands), no vector-memory in the hot loop. Two accumulators per t
// break the fma->rcp->fma chains; 16 unrolled t-chains give the scheduler
// ILP to saturate the trans pipe (machine floor ~14 us).
// launch_bounds(512,4): VGPR cap 128 (need ~96-112); (512,8) capped at 32
// and spilled catastrophically in R2.
// XCD swizzle: bijective, 64 consecutive logical blocks (= 2 (b,h) groups)/XCD.
__global__ __launch_bounds__(512, 4) void attn_v6(
    const float* __restrict__ eq, const float* __restrict__ ekT,
    const __hip_bfloat16* __restrict__ KhT, const float* __restrict__ va_h,
    float* __restrict__ merged)
{
    __shared__ __hip_bfloat16 pA[16][520];   // p in MFMA-A layout source, bf16
    __shared__ float wsum[16][8];

    const int tid = threadIdx.x;
    const int w = tid >> 6;
    const int l = tid & 63;
    const int bid = blockIdx.x;
    const int swz = (bid & 7) * 64 + (bid >> 3);   // bijective: 512 % 8 == 0
    const int t0 = (swz & 31) * 16;
    const int bh_i = swz >> 5;          // 0..15 = b*8 + h
    const int h = bh_i & 7;
    const int b = bh_i >> 3;

    const float* eq_p = eq + ((size_t)bh_i * 512 + t0) * 64;
    const float* ekT_p = ekT + (size_t)bh_i * 64 * 512 + tid;   // this thread's s
    const float* va_p = va_h + h * 64;

    // preload the full ek column for this thread's s: 64 VGPRs, one burst
    float ekv[64];
    #pragma unroll
    for (int j = 0; j < 64; ++j) ekv[j] = ekT_p[j * 512];

    // score S_t = sum_e va_e * rcp(1 + eq[t][e]*ek[e][s]); softmax uses -2*S_t
    float acc[16];
    #pragma unroll
    for (int t = 0; t < 16; ++t) {
        float a0 = 0.f, a1 = 0.f;
        #pragma unroll
        for (int q = 0; q < 8; ++q) {
            float4 e4 = *(const float4*)&eq_p[t * 64 + q * 8];      // uniform -> SGPR
            float4 f4 = *(const float4*)&eq_p[t * 64 + q * 8 + 4];  // uniform -> SGPR
            float4 v4 = *(const float4*)&va_p[q * 8];               // uniform -> SGPR
            float4 u4 = *(const float4*)&va_p[q * 8 + 4];           // uniform -> SGPR
            a0 = fmaf(v4.x, __builtin_amdgcn_rcpf(fmaf(e4.x, ekv[q * 8 + 0], 1.0f)), a0);
            a0 = fmaf(v4.y, __builtin_amdgcn_rcpf(fmaf(e4.y, ekv[q * 8 + 1], 1.0f)), a0);
            a0 = fmaf(v4.z, __builtin_amdgcn_rcpf(fmaf(e4.z, ekv[q * 8 + 2], 1.0f)), a0);
            a0 = fmaf(v4.w, __builtin_amdgcn_rcpf(fmaf(e4.w, ekv[q * 8 + 3], 1.0f)), a0);
            a1 = fmaf(u4.x, __builtin_amdgcn_rcpf(fmaf(f4.x, ekv[q * 8 + 4], 1.0f)), a1);
            a1 = fmaf(u4.y, __builtin_amdgcn_rcpf(fmaf(f4.y, ekv[q * 8 + 5], 1.0f)), a1);
            a1 = fmaf(u4.z, __builtin_amdgcn_rcpf(fmaf(f4.z, ekv[q * 8 + 6], 1.0f)), a1);
            a1 = fmaf(u4.w, __builtin_amdgcn_rcpf(fmaf(f4.w, ekv[q * 8 + 7], 1.0f)), a1);
        }
        acc[t] = a0 + a1;
    }

    // exp (no max-subtract; |score| bounded ~5) + per-t sum across 512 threads
    float ev[16];
    #pragma unroll
    for (int t = 0; t < 16; ++t) {
        float s = __builtin_amdgcn_exp2f(-SCALE2 * acc[t]);   // exp(-2*S_t)
        ev[t] = s;
        #pragma unroll
        for (int off = 32; off > 0; off >>= 1) s += __shfl_xor(s, off, 64);
        if (l == 0) wsum[t][w] = s;
    }
    __syncthreads();
    #pragma unroll
    for (int t = 0; t < 16; ++t) {
        float4 s0 = *(float4*)&wsum[t][0];
        float4 s1 = *(float4*)&wsum[t][4];
        float inv = 1.0f / (((s0.x + s0.y) + (s0.z + s0.w)) + ((s1.x + s1.y) + (s1.z + s1.w)));
        pA[t][tid] = __hip_bfloat16(ev[t] * inv);   // normalized p, bf16
    }
    __syncthreads();

    // P (16x512) @ K (512x64): 4 waves, wave w owns d-range [16w,16w+16)
    if (w < 4) {
        const __hip_bfloat16* kp = KhT + (size_t)bh_i * 64 * 512
                                   + ((size_t)(w * 16 + (l & 15))) * 512 + (l >> 4) * 8;
        const __hip_bfloat16* ap = &pA[l & 15][(l >> 4) * 8];
        floatx4 oacc = {0.f, 0.f, 0.f, 0.f};
        #pragma unroll
        for (int kt = 0; kt < 16; ++kt) {
            short8 af = *(const short8*)(ap + kt * 32);
            short8 bf = *(const short8*)(kp + kt * 32);
            oacc = __builtin_amdgcn_mfma_f32_16x16x32_bf16(af, bf, oacc, 0, 0, 0);
        }
        const int row = (l >> 4) * 4;        // t_local base
        const int col = w * 16 + (l & 15);   // d
        float* mp = merged + ((size_t)(b * 512 + t0 + row)) * 512 + h * 64 + col;
        #pragma unroll
        for (int r = 0; r < 4; ++r) mp[r * 512] = oacc[r];
    }
}

// ================= output projection: C = A@Wo + bo =================
// R1-measured shape: 32x64 tiles -> 256 blocks, 2x4/thread, register prefetch.
__global__ __launch_bounds__(256) void gemm_out(
    const float* __restrict__ A, const float* __restrict__ W,
    const float* __restrict__ bias, float* __restrict__ C)
{
    __shared__ float As[32][36];   // [k][m]
    __shared__ float Bs[32][68];   // [k][n]

    const int tid = threadIdx.x;
    const int n0 = blockIdx.x * 64;
    const int m0 = blockIdx.y * 32;

    const int arow = tid >> 3;          // m 0..31
    const int acol = (tid & 7) * 4;     // k base 0..28
    const int bkk = tid >> 3;           // k 0..31
    const int bn = (tid & 7) * 8;       // n base

    const int ti = tid >> 4;            // m = 2*ti
    const int tj = tid & 15;            // n = 4*tj

    float4 acc0 = make_float4(0.f, 0.f, 0.f, 0.f);
    float4 acc1 = make_float4(0.f, 0.f, 0.f, 0.f);

    float4 av  = *(const float4*)&A[(m0 + arow) * 512 + acol];
    float4 bv0 = *(const float4*)&W[bkk * 512 + n0 + bn];
    float4 bv1 = *(const float4*)&W[bkk * 512 + n0 + bn + 4];

    for (int k0 = 0; k0 < 512; k0 += 32) {
        __syncthreads();
        As[acol + 0][arow] = av.x;
        As[acol + 1][arow] = av.y;
        As[acol + 2][arow] = av.z;
        As[acol + 3][arow] = av.w;
        *(float4*)&Bs[bkk][bn] = bv0;
        *(float4*)&Bs[bkk][bn + 4] = bv1;
        __syncthreads();
        if (k0 + 32 < 512) {
            av  = *(const float4*)&A[(m0 + arow) * 512 + k0 + 32 + acol];
            bv0 = *(const float4*)&W[(k0 + 32 + bkk) * 512 + n0 + bn];
            bv1 = *(const float4*)&W[(k0 + 32 + bkk) * 512 + n0 + bn + 4];
        }
        #pragma unroll
        for (int kk = 0; kk < 32; ++kk) {
            float2 a2 = *(const float2*)&As[kk][2 * ti];
            float4 b4 = *(const float4*)&Bs[kk][4 * tj];
            acc0.x = fmaf(a2.x, b4.x, acc0.x);
            acc0.y = fmaf(a2.x, b4.y, acc0.y);
            acc0.z = fmaf(a2.x, b4.z, acc0.z);
            acc0.w = fmaf(a2.x, b4.w, acc0.w);
            acc1.x = fmaf(a2.y, b4.x, acc1.x);
            acc1.y = fmaf(a2.y, b4.y, acc1.y);
            acc1.z = fmaf(a2.y, b4.z, acc1.z);
            acc1.w = fmaf(a2.y, b4.w, acc1.w);
        }
    }
    float4 bb = *(const float4*)&bias[n0 + 4 * tj];
    float4 o0, o1;
    o0.x = acc0.x + bb.x; o0.y = acc0.y + bb.y; o0.z = acc0.z + bb.z; o0.w = acc0.w + bb.w;
    o1.x = acc1.x + bb.x; o1.y = acc1.y + bb.y; o1.z = acc1.z + bb.z; o1.w = acc1.w + bb.w;
    *(float4*)&C[(m0 + 2 * ti) * 512 + n0 + 4 * tj] = o0;
    *(float4*)&C[(m0 + 2 * ti + 1) * 512 + n0 + 4 * tj] = o1;
}

extern "C" void kernel_launch(void* const* d_in, const int* in_sizes, int n_in,
                              void* d_out, int out_size, void* d_ws, size_t ws_size,
                              hipStream_t stream) {
    (void)in_sizes; (void)n_in; (void)out_size; (void)ws_size;
    const float* query = (const float*)d_in[0];
    const float* key   = (const float*)d_in[1];
    // d_in[2] (value), d_in[7] (Wv), d_in[8] (bv): dead in the reference
    const float* Wq   = (const float*)d_in[3];
    const float* bq   = (const float*)d_in[4];
    const float* Wk   = (const float*)d_in[5];
    const float* bk   = (const float*)d_in[6];
    const float* Wq_h = (const float*)d_in[9];
    const float* Wk_h = (const float*)d_in[10];
    const float* va_h = (const float*)d_in[11];
    const float* b_h  = (const float*)d_in[12];
    const float* Wo   = (const float*)d_in[13];
    const float* bo   = (const float*)d_in[14];

    float* out = (float*)d_out;
    float* ws = (float*)d_ws;
    const int SZ = 1024 * 512;        // 524288 floats
    float* eqb     = ws;
    float* ekTb    = eqb + SZ;
    float* mergedb = ekTb + SZ;
    __hip_bfloat16* KhTb = (__hip_bfloat16*)(mergedb + SZ);   // 524288 bf16

    // fused: {Q,K} = In@W+b, then per-head transform -> eq / ekT / KhT
    qk_head_fused<<<dim3(8, 16, 2), 256, 0, stream>>>(query, key, Wq, bq, Wk, bk,
                                                      Wq_h, Wk_h, b_h,
                                                      eqb, ekTb, KhTb);
    // scores -> softmax -> P@K (MFMA); 512 blocks, XCD-swizzled
    attn_v6<<<dim3(512, 1, 1), 512, 0, stream>>>(eqb, ekTb, KhTb, va_h, mergedb);
    // out = merged@Wo + bo  (256 blocks)
    gemm_out<<<dim3(8, 32, 1), 256, 0, stream>>>(mergedb, Wo, bo, out);
}

// Round 6
// 159.426 us; speedup vs baseline: 2.0909x; 1.1318x over previous
//
#include <hip/hip_runtime.h>
#include <hip/hip_bf16.h>

#define T_SEQ 512
#define NH 8
#define DEPTH 64
#define UNITS_ 512
#define SCALE2 2.8853900817779268f   // 2*log2(e)
#define LOG2E 1.4426950408889634f

typedef __attribute__((ext_vector_type(4))) short bshort4;
typedef __attribute__((ext_vector_type(8))) short short8;
typedef __attribute__((ext_vector_type(4))) float floatx4;

// ---- bf16 helpers: split fp32 x = hi + lo (both bf16-representable) ----
static __device__ __forceinline__ short bfh(float x) {
    __hip_bfloat16 b(x);
    return *(short*)&b;
}
static __device__ __forceinline__ float bff(short s) {
    unsigned u = ((unsigned)(unsigned short)s) << 16;
    float f;
    __builtin_memcpy(&f, &u, 4);
    return f;
}
static __device__ __forceinline__ void split4(float4 x, bshort4& h, bshort4& l) {
    union { bshort4 v; short s[4]; } H, L;
    float xs[4] = {x.x, x.y, x.z, x.w};
    #pragma unroll
    for (int i = 0; i < 4; ++i) {
        short hh = bfh(xs[i]);
        H.s[i] = hh;
        L.s[i] = bfh(xs[i] - bff(hh));
    }
    h = H.v; l = L.v;
}
static __device__ __forceinline__ void split8(float4 x, float4 y, short8& h, short8& l) {
    union { short8 v; short s[8]; } H, L;
    float xs[8] = {x.x, x.y, x.z, x.w, y.x, y.y, y.z, y.w};
    #pragma unroll
    for (int i = 0; i < 8; ++i) {
        short hh = bfh(xs[i]);
        H.s[i] = hh;
        L.s[i] = bfh(xs[i] - bff(hh));
    }
    h = H.v; l = L.v;
}

// ======= fused QK projection (split-bf16 MFMA) + per-head transform =======
// 512 threads, 8 waves. Tile 64m x 64n, K-step 64, 3-pass split-bf16 MFMA.
// wave wv: m-strip (wv&3)*16, n-half (wv>>2)*32 (2 n-tiles of 16).
// Stage 2 (fp32 VALU): C^T+bias staged in LDS, per-head 64x64 transform,
// outputs eq / ekT / KhT exactly as before (layouts unchanged).
__global__ __launch_bounds__(512) void qk_head_mfma(
    const float* __restrict__ query, const float* __restrict__ key,
    const float* __restrict__ Wq, const float* __restrict__ bq,
    const float* __restrict__ Wk, const float* __restrict__ bk,
    const float* __restrict__ Wq_h, const float* __restrict__ Wk_h,
    const float* __restrict__ bh,
    float* __restrict__ eq, float* __restrict__ ekT,
    __hip_bfloat16* __restrict__ KhT)
{
    // stage1: Ah/Al/Wh/Wl bf16 [64][72] each (pitch 144B, 16B-mult, 4dw-shift/row)
    // stage2 (after barrier, aliased): S1 = C^T+bias fp32[64][68], S2 = Wh_head fp32[64][68]
    __shared__ __align__(16) short BUF[256 * 72];
    short (*Ah)[72] = (short(*)[72])BUF;
    short (*Al)[72] = (short(*)[72])(BUF + 64 * 72);
    short (*Wh)[72] = (short(*)[72])(BUF + 128 * 72);
    short (*Wl)[72] = (short(*)[72])(BUF + 192 * 72);
    float (*S1)[68] = (float(*)[68])BUF;                 // 17408 B
    float (*S2)[68] = (float(*)[68])(BUF + 8704);        // 17408 B (byte off 17408)

    const int tid = threadIdx.x;
    const int which = blockIdx.z;            // 0 = Q path, 1 = K path
    const int h  = blockIdx.x;
    const int m0 = blockIdx.y * 64;          // row in [0,1024): b*512 + t
    const int n0 = h * 64;
    const int b  = m0 >> 9;
    const int t0 = m0 & 511;
    const int bh_i = b * NH + h;

    const float* In   = which ? key : query;
    const float* W    = which ? Wk  : Wq;
    const float* bias = which ? bk  : bq;
    const float* Wp   = (which ? Wk_h : Wq_h) + h * 4096;

    const int wv = tid >> 6;            // wave 0..7
    const int l  = tid & 63;
    const int ms = (wv & 3) * 16;       // m-strip
    const int ns = (wv >> 2) * 32;      // n-half
    const int fr = l & 15;              // fragment row/col index
    const int fq = l >> 4;              // k-slice quarter

    // staging indices
    const int arow = tid >> 3;          // 0..63
    const int acol = (tid & 7) * 8;     // 0..56
    const int wn   = tid & 63;          // W: n 0..63 (lane-coalesced)
    const int wkb  = (tid >> 6) * 8;    // W: k base 0..56

    // per-head weight tile prefetch (held in regs through stage 1)
    const int hwrow = tid >> 3;         // d 0..63
    const int hwcol = (tid & 7) * 8;    // e base
    float4 whA = *(const float4*)&Wp[hwrow * 64 + hwcol];
    float4 whB = *(const float4*)&Wp[hwrow * 64 + hwcol + 4];

    // bias per lane for fragment store
    const float bb0 = bias[n0 + ns + fr];
    const float bb1 = bias[n0 + ns + 16 + fr];

    floatx4 acc0 = {0.f, 0.f, 0.f, 0.f};
    floatx4 acc1 = {0.f, 0.f, 0.f, 0.f};

    // prefetch k-tile 0
    float4 a0 = *(const float4*)&In[(m0 + arow) * 512 + acol];
    float4 a1 = *(const float4*)&In[(m0 + arow) * 512 + acol + 4];
    float wr[8];
    #pragma unroll
    for (int i = 0; i < 8; ++i) wr[i] = W[(wkb + i) * 512 + n0 + wn];

    for (int k0 = 0; k0 < 512; k0 += 64) {
        __syncthreads();
        {   // convert + stage
            short8 h8, l8;
            split8(a0, a1, h8, l8);
            *(short8*)&Ah[arow][acol] = h8;
            *(short8*)&Al[arow][acol] = l8;
            union { short8 v; short s[8]; } WH, WL;
            #pragma unroll
            for (int i = 0; i < 8; ++i) {
                short hh = bfh(wr[i]);
                WH.s[i] = hh;
                WL.s[i] = bfh(wr[i] - bff(hh));
            }
            *(short8*)&Wh[wn][wkb] = WH.v;
            *(short8*)&Wl[wn][wkb] = WL.v;
        }
        __syncthreads();
        if (k0 + 64 < 512) {            // prefetch next k-tile under the MFMAs
            a0 = *(const float4*)&In[(m0 + arow) * 512 + k0 + 64 + acol];
            a1 = *(const float4*)&In[(m0 + arow) * 512 + k0 + 64 + acol + 4];
            #pragma unroll
            for (int i = 0; i < 8; ++i)
                wr[i] = W[(k0 + 64 + wkb + i) * 512 + n0 + wn];
        }
        #pragma unroll
        for (int kc = 0; kc < 2; ++kc) {
            const int ko = kc * 32 + fq * 8;
            short8 ah  = *(const short8*)&Ah[ms + fr][ko];
            short8 al  = *(const short8*)&Al[ms + fr][ko];
            short8 w0h = *(const short8*)&Wh[ns + fr][ko];
            short8 w0l = *(const short8*)&Wl[ns + fr][ko];
            short8 w1h = *(const short8*)&Wh[ns + 16 + fr][ko];
            short8 w1l = *(const short8*)&Wl[ns + 16 + fr][ko];
            acc0 = __builtin_amdgcn_mfma_f32_16x16x32_bf16(ah, w0h, acc0, 0, 0, 0);
            acc1 = __builtin_amdgcn_mfma_f32_16x16x32_bf16(ah, w1h, acc1, 0, 0, 0);
            acc0 = __builtin_amdgcn_mfma_f32_16x16x32_bf16(ah, w0l, acc0, 0, 0, 0);
            acc1 = __builtin_amdgcn_mfma_f32_16x16x32_bf16(ah, w1l, acc1, 0, 0, 0);
            acc0 = __builtin_amdgcn_mfma_f32_16x16x32_bf16(al, w0h, acc0, 0, 0, 0);
            acc1 = __builtin_amdgcn_mfma_f32_16x16x32_bf16(al, w1h, acc1, 0, 0, 0);
        }
    }

    // ---- stage 2: per-head 64x64 transform (fp32 VALU) ----
    __syncthreads();   // all MFMA LDS reads done; BUF is now repurposed
    // C^T (+bias) into S1[n][m]; per-head weights into S2[d][e]
    #pragma unroll
    for (int r = 0; r < 4; ++r) {
        S1[ns + fr][ms + fq * 4 + r]      = acc0[r] + bb0;
        S1[ns + 16 + fr][ms + fq * 4 + r] = acc1[r] + bb1;
    }
    *(float4*)&S2[hwrow][hwcol]     = whA;
    *(float4*)&S2[hwrow][hwcol + 4] = whB;
    __syncthreads();

    const int ti = tid >> 4;            // 0..31 -> rows 2ti, 2ti+1
    const int tj = tid & 15;            // cols 4tj..4tj+3
    float4 qa0 = make_float4(0.f, 0.f, 0.f, 0.f);
    float4 qa1 = make_float4(0.f, 0.f, 0.f, 0.f);
    #pragma unroll 8
    for (int d = 0; d < 64; ++d) {
        float2 a2 = *(const float2*)&S1[d][2 * ti];
        float4 b4 = *(const float4*)&S2[d][4 * tj];
        qa0.x = fmaf(a2.x, b4.x, qa0.x);
        qa0.y = fmaf(a2.x, b4.y, qa0.y);
        qa0.z = fmaf(a2.x, b4.z, qa0.z);
        qa0.w = fmaf(a2.x, b4.w, qa0.w);
        qa1.x = fmaf(a2.y, b4.x, qa1.x);
        qa1.y = fmaf(a2.y, b4.y, qa1.y);
        qa1.z = fmaf(a2.y, b4.z, qa1.z);
        qa1.w = fmaf(a2.y, b4.w, qa1.w);
    }

    if (which == 0) {
        float* outp = eq + ((size_t)bh_i * 512 + t0) * 64;
        float4 o0, o1;
        o0.x = __builtin_amdgcn_exp2f(SCALE2 * qa0.x);
        o0.y = __builtin_amdgcn_exp2f(SCALE2 * qa0.y);
        o0.z = __builtin_amdgcn_exp2f(SCALE2 * qa0.z);
        o0.w = __builtin_amdgcn_exp2f(SCALE2 * qa0.w);
        o1.x = __builtin_amdgcn_exp2f(SCALE2 * qa1.x);
        o1.y = __builtin_amdgcn_exp2f(SCALE2 * qa1.y);
        o1.z = __builtin_amdgcn_exp2f(SCALE2 * qa1.z);
        o1.w = __builtin_amdgcn_exp2f(SCALE2 * qa1.w);
        *(float4*)&outp[(2 * ti + 0) * 64 + 4 * tj] = o0;
        *(float4*)&outp[(2 * ti + 1) * 64 + 4 * tj] = o1;
        return;
    }

    // which == 1: ekT (transposed, exp2'd, +b_h) and KhT (bf16 of C^T)
    float4 bhv = *(const float4*)&bh[h * 64 + 4 * tj];
    __syncthreads();   // all threads done reading S2 as per-head weights
    S2[4 * tj + 0][2 * ti + 0] = __builtin_amdgcn_exp2f(SCALE2 * (qa0.x + bhv.x));
    S2[4 * tj + 0][2 * ti + 1] = __builtin_amdgcn_exp2f(SCALE2 * (qa1.x + bhv.x));
    S2[4 * tj + 1][2 * ti + 0] = __builtin_amdgcn_exp2f(SCALE2 * (qa0.y + bhv.y));
    S2[4 * tj + 1][2 * ti + 1] = __builtin_amdgcn_exp2f(SCALE2 * (qa1.y + bhv.y));
    S2[4 * tj + 2][2 * ti + 0] = __builtin_amdgcn_exp2f(SCALE2 * (qa0.z + bhv.z));
    S2[4 * tj + 2][2 * ti + 1] = __builtin_amdgcn_exp2f(SCALE2 * (qa1.z + bhv.z));
    S2[4 * tj + 3][2 * ti + 0] = __builtin_amdgcn_exp2f(SCALE2 * (qa0.w + bhv.w));
    S2[4 * tj + 3][2 * ti + 1] = __builtin_amdgcn_exp2f(SCALE2 * (qa1.w + bhv.w));
    __syncthreads();

    const int dd = tid >> 3;            // e (or d) 0..63
    const int sc = (tid & 7) * 8;       // s chunk
    float* ekp = ekT + ((size_t)bh_i * 64 + dd) * 512 + t0 + sc;
    *(float4*)&ekp[0] = *(float4*)&S2[dd][sc];
    *(float4*)&ekp[4] = *(float4*)&S2[dd][sc + 4];

    __hip_bfloat16* kp = KhT + ((size_t)bh_i * 64 + dd) * 512 + t0 + sc;
    union { short8 v; short s[8]; } pk;
    #pragma unroll
    for (int i = 0; i < 8; ++i) pk.s[i] = bfh(S1[dd][sc + i]);
    *(short8*)kp = pk.v;
}

// ============ additive-attention core (register score + MFMA P@K) ============
// UNCHANGED from verified R3 build (59 us).
__global__ __launch_bounds__(512, 4) void attn_v6(
    const float* __restrict__ eq, const float* __restrict__ ekT,
    const __hip_bfloat16* __restrict__ KhT, const float* __restrict__ va_h,
    float* __restrict__ merged)
{
    __shared__ __hip_bfloat16 pA[16][520];   // p in MFMA-A layout source, bf16
    __shared__ float wsum[16][8];

    const int tid = threadIdx.x;
    const int w = tid >> 6;
    const int l = tid & 63;
    const int bid = blockIdx.x;
    const int swz = (bid & 7) * 64 + (bid >> 3);   // bijective: 512 % 8 == 0
    const int t0 = (swz & 31) * 16;
    const int bh_i = swz >> 5;          // 0..15 = b*8 + h
    const int h = bh_i & 7;
    const int b = bh_i >> 3;

    const float* eq_p = eq + ((size_t)bh_i * 512 + t0) * 64;
    const float* ekT_p = ekT + (size_t)bh_i * 64 * 512 + tid;   // this thread's s
    const float* va_p = va_h + h * 64;

    // preload the full ek column for this thread's s
    float ekv[64];
    #pragma unroll
    for (int j = 0; j < 64; ++j) ekv[j] = ekT_p[j * 512];

    // score S_t = sum_e va_e * rcp(1 + eq[t][e]*ek[e][s]); softmax uses -2*S_t
    float acc[16];
    #pragma unroll
    for (int t = 0; t < 16; ++t) {
        float a0 = 0.f, a1 = 0.f;
        #pragma unroll
        for (int q = 0; q < 8; ++q) {
            float4 e4 = *(const float4*)&eq_p[t * 64 + q * 8];      // uniform -> SGPR
            float4 f4 = *(const float4*)&eq_p[t * 64 + q * 8 + 4];  // uniform -> SGPR
            float4 v4 = *(const float4*)&va_p[q * 8];               // uniform -> SGPR
            float4 u4 = *(const float4*)&va_p[q * 8 + 4];           // uniform -> SGPR
            a0 = fmaf(v4.x, __builtin_amdgcn_rcpf(fmaf(e4.x, ekv[q * 8 + 0], 1.0f)), a0);
            a0 = fmaf(v4.y, __builtin_amdgcn_rcpf(fmaf(e4.y, ekv[q * 8 + 1], 1.0f)), a0);
            a0 = fmaf(v4.z, __builtin_amdgcn_rcpf(fmaf(e4.z, ekv[q * 8 + 2], 1.0f)), a0);
            a0 = fmaf(v4.w, __builtin_amdgcn_rcpf(fmaf(e4.w, ekv[q * 8 + 3], 1.0f)), a0);
            a1 = fmaf(u4.x, __builtin_amdgcn_rcpf(fmaf(f4.x, ekv[q * 8 + 4], 1.0f)), a1);
            a1 = fmaf(u4.y, __builtin_amdgcn_rcpf(fmaf(f4.y, ekv[q * 8 + 5], 1.0f)), a1);
            a1 = fmaf(u4.z, __builtin_amdgcn_rcpf(fmaf(f4.z, ekv[q * 8 + 6], 1.0f)), a1);
            a1 = fmaf(u4.w, __builtin_amdgcn_rcpf(fmaf(f4.w, ekv[q * 8 + 7], 1.0f)), a1);
        }
        acc[t] = a0 + a1;
    }

    // exp (no max-subtract; |score| bounded ~5) + per-t sum across 512 threads
    float ev[16];
    #pragma unroll
    for (int t = 0; t < 16; ++t) {
        float s = __builtin_amdgcn_exp2f(-SCALE2 * acc[t]);   // exp(-2*S_t)
        ev[t] = s;
        #pragma unroll
        for (int off = 32; off > 0; off >>= 1) s += __shfl_xor(s, off, 64);
        if (l == 0) wsum[t][w] = s;
    }
    __syncthreads();
    #pragma unroll
    for (int t = 0; t < 16; ++t) {
        float4 s0 = *(float4*)&wsum[t][0];
        float4 s1 = *(float4*)&wsum[t][4];
        float inv = 1.0f / (((s0.x + s0.y) + (s0.z + s0.w)) + ((s1.x + s1.y) + (s1.z + s1.w)));
        pA[t][tid] = __hip_bfloat16(ev[t] * inv);   // normalized p, bf16
    }
    __syncthreads();

    // P (16x512) @ K (512x64): 4 waves, wave w owns d-range [16w,16w+16)
    if (w < 4) {
        const __hip_bfloat16* kp = KhT + (size_t)bh_i * 64 * 512
                                   + ((size_t)(w * 16 + (l & 15))) * 512 + (l >> 4) * 8;
        const __hip_bfloat16* ap = &pA[l & 15][(l >> 4) * 8];
        floatx4 oacc = {0.f, 0.f, 0.f, 0.f};
        #pragma unroll
        for (int kt = 0; kt < 16; ++kt) {
            short8 af = *(const short8*)(ap + kt * 32);
            short8 bf = *(const short8*)(kp + kt * 32);
            oacc = __builtin_amdgcn_mfma_f32_16x16x32_bf16(af, bf, oacc, 0, 0, 0);
        }
        const int row = (l >> 4) * 4;        // t_local base
        const int col = w * 16 + (l & 15);   // d
        float* mp = merged + ((size_t)(b * 512 + t0 + row)) * 512 + h * 64 + col;
        #pragma unroll
        for (int r = 0; r < 4; ++r) mp[r * 512] = oacc[r];
    }
}

// ======= output projection (split-bf16 MFMA): C = A@Wo + bo =======
// 512 threads, 8 waves. Tile 32m x 64n -> 256 blocks. K-step 64.
// wave wv: m-strip (wv&1)*16, n-tile (wv>>1)*16.
__global__ __launch_bounds__(512) void gemm_out_mfma(
    const float* __restrict__ A, const float* __restrict__ W,
    const float* __restrict__ bias, float* __restrict__ C)
{
    __shared__ __align__(16) short BUF[192 * 72];
    short (*Ah)[72] = (short(*)[72])BUF;
    short (*Al)[72] = (short(*)[72])(BUF + 32 * 72);
    short (*Wh)[72] = (short(*)[72])(BUF + 64 * 72);
    short (*Wl)[72] = (short(*)[72])(BUF + 128 * 72);

    const int tid = threadIdx.x;
    const int n0 = blockIdx.x * 64;
    const int m0 = blockIdx.y * 32;
    const int wv = tid >> 6;
    const int l  = tid & 63;
    const int ms = (wv & 1) * 16;
    const int ns = (wv >> 1) * 16;
    const int fr = l & 15;
    const int fq = l >> 4;

    const int arow = tid >> 4;          // 0..31
    const int acol = (tid & 15) * 4;    // 0..60
    const int wn   = tid & 63;
    const int wkb  = (tid >> 6) * 8;

    const float bb = bias[n0 + ns + fr];
    floatx4 acc = {0.f, 0.f, 0.f, 0.f};

    float4 a0 = *(const float4*)&A[(m0 + arow) * 512 + acol];
    float wr[8];
    #pragma unroll
    for (int i = 0; i < 8; ++i) wr[i] = W[(wkb + i) * 512 + n0 + wn];

    for (int k0 = 0; k0 < 512; k0 += 64) {
        __syncthreads();
        {
            bshort4 h4, l4;
            split4(a0, h4, l4);
            *(bshort4*)&Ah[arow][acol] = h4;
            *(bshort4*)&Al[arow][acol] = l4;
            union { short8 v; short s[8]; } WH, WL;
            #pragma unroll
            for (int i = 0; i < 8; ++i) {
                short hh = bfh(wr[i]);
                WH.s[i] = hh;
                WL.s[i] = bfh(wr[i] - bff(hh));
            }
            *(short8*)&Wh[wn][wkb] = WH.v;
            *(short8*)&Wl[wn][wkb] = WL.v;
        }
        __syncthreads();
        if (k0 + 64 < 512) {
            a0 = *(const float4*)&A[(m0 + arow) * 512 + k0 + 64 + acol];
            #pragma unroll
            for (int i = 0; i < 8; ++i)
                wr[i] = W[(k0 + 64 + wkb + i) * 512 + n0 + wn];
        }
        #pragma unroll
        for (int kc = 0; kc < 2; ++kc) {
            const int ko = kc * 32 + fq * 8;
            short8 ah = *(const short8*)&Ah[ms + fr][ko];
            short8 al = *(const short8*)&Al[ms + fr][ko];
            short8 wh = *(const short8*)&Wh[ns + fr][ko];
            short8 wl = *(const short8*)&Wl[ns + fr][ko];
            acc = __builtin_amdgcn_mfma_f32_16x16x32_bf16(ah, wh, acc, 0, 0, 0);
            acc = __builtin_amdgcn_mfma_f32_16x16x32_bf16(ah, wl, acc, 0, 0, 0);
            acc = __builtin_amdgcn_mfma_f32_16x16x32_bf16(al, wh, acc, 0, 0, 0);
        }
    }

    const int mrow = m0 + ms + fq * 4;
    const int ncol = n0 + ns + fr;
    #pragma unroll
    for (int r = 0; r < 4; ++r)
        C[(size_t)(mrow + r) * 512 + ncol] = acc[r] + bb;
}

extern "C" void kernel_launch(void* const* d_in, const int* in_sizes, int n_in,
                              void* d_out, int out_size, void* d_ws, size_t ws_size,
                              hipStream_t stream) {
    (void)in_sizes; (void)n_in; (void)out_size; (void)ws_size;
    const float* query = (const float*)d_in[0];
    const float* key   = (const float*)d_in[1];
    // d_in[2] (value), d_in[7] (Wv), d_in[8] (bv): dead in the reference
    const float* Wq   = (const float*)d_in[3];
    const float* bq   = (const float*)d_in[4];
    const float* Wk   = (const float*)d_in[5];
    const float* bk   = (const float*)d_in[6];
    const float* Wq_h = (const float*)d_in[9];
    const float* Wk_h = (const float*)d_in[10];
    const float* va_h = (const float*)d_in[11];
    const float* b_h  = (const float*)d_in[12];
    const float* Wo   = (const float*)d_in[13];
    const float* bo   = (const float*)d_in[14];

    float* out = (float*)d_out;
    float* ws = (float*)d_ws;
    const int SZ = 1024 * 512;        // 524288 floats
    float* eqb     = ws;
    float* ekTb    = eqb + SZ;
    float* mergedb = ekTb + SZ;
    __hip_bfloat16* KhTb = (__hip_bfloat16*)(mergedb + SZ);   // 524288 bf16

    // fused: {Q,K} = In@W+b (split-bf16 MFMA), per-head transform -> eq/ekT/KhT
    qk_head_mfma<<<dim3(8, 16, 2), 512, 0, stream>>>(query, key, Wq, bq, Wk, bk,
                                                     Wq_h, Wk_h, b_h,
                                                     eqb, ekTb, KhTb);
    // scores -> softmax -> P@K (MFMA); 512 blocks, XCD-swizzled
    attn_v6<<<dim3(512, 1, 1), 512, 0, stream>>>(eqb, ekTb, KhTb, va_h, mergedb);
    // out = merged@Wo + bo (split-bf16 MFMA, 256 blocks)
    gemm_out_mfma<<<dim3(8, 32, 1), 512, 0, stream>>>(mergedb, Wo, bo, out);
}

// Round 7
// 157.326 us; speedup vs baseline: 2.1188x; 1.0133x over previous
//
#include <hip/hip_runtime.h>
#include <hip/hip_bf16.h>

#define T_SEQ 512
#define NH 8
#define DEPTH 64
#define UNITS_ 512
#define SCALE2 2.8853900817779268f   // 2*log2(e)
#define LOG2E 1.4426950408889634f

typedef __attribute__((ext_vector_type(4))) short bshort4;
typedef __attribute__((ext_vector_type(8))) short short8;
typedef __attribute__((ext_vector_type(4))) float floatx4;

// ---- bf16 helpers: split fp32 x = hi + lo (both bf16-representable) ----
static __device__ __forceinline__ short bfh(float x) {
    __hip_bfloat16 b(x);
    return *(short*)&b;
}
static __device__ __forceinline__ float bff(short s) {
    unsigned u = ((unsigned)(unsigned short)s) << 16;
    float f;
    __builtin_memcpy(&f, &u, 4);
    return f;
}
static __device__ __forceinline__ void split4(float4 x, bshort4& h, bshort4& l) {
    union { bshort4 v; short s[4]; } H, L;
    float xs[4] = {x.x, x.y, x.z, x.w};
    #pragma unroll
    for (int i = 0; i < 4; ++i) {
        short hh = bfh(xs[i]);
        H.s[i] = hh;
        L.s[i] = bfh(xs[i] - bff(hh));
    }
    h = H.v; l = L.v;
}
static __device__ __forceinline__ void split8(float4 x, float4 y, short8& h, short8& l) {
    union { short8 v; short s[8]; } H, L;
    float xs[8] = {x.x, x.y, x.z, x.w, y.x, y.y, y.z, y.w};
    #pragma unroll
    for (int i = 0; i < 8; ++i) {
        short hh = bfh(xs[i]);
        H.s[i] = hh;
        L.s[i] = bfh(xs[i] - bff(hh));
    }
    h = H.v; l = L.v;
}

// ======= fused QK projection (split-bf16 MFMA) + per-head transform =======
// UNCHANGED from verified R5 build.
__global__ __launch_bounds__(512) void qk_head_mfma(
    const float* __restrict__ query, const float* __restrict__ key,
    const float* __restrict__ Wq, const float* __restrict__ bq,
    const float* __restrict__ Wk, const float* __restrict__ bk,
    const float* __restrict__ Wq_h, const float* __restrict__ Wk_h,
    const float* __restrict__ bh,
    float* __restrict__ eq, float* __restrict__ ekT,
    __hip_bfloat16* __restrict__ KhT)
{
    __shared__ __align__(16) short BUF[256 * 72];
    short (*Ah)[72] = (short(*)[72])BUF;
    short (*Al)[72] = (short(*)[72])(BUF + 64 * 72);
    short (*Wh)[72] = (short(*)[72])(BUF + 128 * 72);
    short (*Wl)[72] = (short(*)[72])(BUF + 192 * 72);
    float (*S1)[68] = (float(*)[68])BUF;
    float (*S2)[68] = (float(*)[68])(BUF + 8704);

    const int tid = threadIdx.x;
    const int which = blockIdx.z;            // 0 = Q path, 1 = K path
    const int h  = blockIdx.x;
    const int m0 = blockIdx.y * 64;          // row in [0,1024): b*512 + t
    const int n0 = h * 64;
    const int b  = m0 >> 9;
    const int t0 = m0 & 511;
    const int bh_i = b * NH + h;

    const float* In   = which ? key : query;
    const float* W    = which ? Wk  : Wq;
    const float* bias = which ? bk  : bq;
    const float* Wp   = (which ? Wk_h : Wq_h) + h * 4096;

    const int wv = tid >> 6;            // wave 0..7
    const int l  = tid & 63;
    const int ms = (wv & 3) * 16;       // m-strip
    const int ns = (wv >> 2) * 32;      // n-half
    const int fr = l & 15;              // fragment row/col index
    const int fq = l >> 4;              // k-slice quarter

    const int arow = tid >> 3;          // 0..63
    const int acol = (tid & 7) * 8;     // 0..56
    const int wn   = tid & 63;          // W: n 0..63 (lane-coalesced)
    const int wkb  = (tid >> 6) * 8;    // W: k base 0..56

    const int hwrow = tid >> 3;         // d 0..63
    const int hwcol = (tid & 7) * 8;    // e base
    float4 whA = *(const float4*)&Wp[hwrow * 64 + hwcol];
    float4 whB = *(const float4*)&Wp[hwrow * 64 + hwcol + 4];

    const float bb0 = bias[n0 + ns + fr];
    const float bb1 = bias[n0 + ns + 16 + fr];

    floatx4 acc0 = {0.f, 0.f, 0.f, 0.f};
    floatx4 acc1 = {0.f, 0.f, 0.f, 0.f};

    float4 a0 = *(const float4*)&In[(m0 + arow) * 512 + acol];
    float4 a1 = *(const float4*)&In[(m0 + arow) * 512 + acol + 4];
    float wr[8];
    #pragma unroll
    for (int i = 0; i < 8; ++i) wr[i] = W[(wkb + i) * 512 + n0 + wn];

    for (int k0 = 0; k0 < 512; k0 += 64) {
        __syncthreads();
        {   // convert + stage
            short8 h8, l8;
            split8(a0, a1, h8, l8);
            *(short8*)&Ah[arow][acol] = h8;
            *(short8*)&Al[arow][acol] = l8;
            union { short8 v; short s[8]; } WH, WL;
            #pragma unroll
            for (int i = 0; i < 8; ++i) {
                short hh = bfh(wr[i]);
                WH.s[i] = hh;
                WL.s[i] = bfh(wr[i] - bff(hh));
            }
            *(short8*)&Wh[wn][wkb] = WH.v;
            *(short8*)&Wl[wn][wkb] = WL.v;
        }
        __syncthreads();
        if (k0 + 64 < 512) {            // prefetch next k-tile under the MFMAs
            a0 = *(const float4*)&In[(m0 + arow) * 512 + k0 + 64 + acol];
            a1 = *(const float4*)&In[(m0 + arow) * 512 + k0 + 64 + acol + 4];
            #pragma unroll
            for (int i = 0; i < 8; ++i)
                wr[i] = W[(k0 + 64 + wkb + i) * 512 + n0 + wn];
        }
        #pragma unroll
        for (int kc = 0; kc < 2; ++kc) {
            const int ko = kc * 32 + fq * 8;
            short8 ah  = *(const short8*)&Ah[ms + fr][ko];
            short8 al  = *(const short8*)&Al[ms + fr][ko];
            short8 w0h = *(const short8*)&Wh[ns + fr][ko];
            short8 w0l = *(const short8*)&Wl[ns + fr][ko];
            short8 w1h = *(const short8*)&Wh[ns + 16 + fr][ko];
            short8 w1l = *(const short8*)&Wl[ns + 16 + fr][ko];
            acc0 = __builtin_amdgcn_mfma_f32_16x16x32_bf16(ah, w0h, acc0, 0, 0, 0);
            acc1 = __builtin_amdgcn_mfma_f32_16x16x32_bf16(ah, w1h, acc1, 0, 0, 0);
            acc0 = __builtin_amdgcn_mfma_f32_16x16x32_bf16(ah, w0l, acc0, 0, 0, 0);
            acc1 = __builtin_amdgcn_mfma_f32_16x16x32_bf16(ah, w1l, acc1, 0, 0, 0);
            acc0 = __builtin_amdgcn_mfma_f32_16x16x32_bf16(al, w0h, acc0, 0, 0, 0);
            acc1 = __builtin_amdgcn_mfma_f32_16x16x32_bf16(al, w1h, acc1, 0, 0, 0);
        }
    }

    // ---- stage 2: per-head 64x64 transform (fp32 VALU) ----
    __syncthreads();
    #pragma unroll
    for (int r = 0; r < 4; ++r) {
        S1[ns + fr][ms + fq * 4 + r]      = acc0[r] + bb0;
        S1[ns + 16 + fr][ms + fq * 4 + r] = acc1[r] + bb1;
    }
    *(float4*)&S2[hwrow][hwcol]     = whA;
    *(float4*)&S2[hwrow][hwcol + 4] = whB;
    __syncthreads();

    const int ti = tid >> 4;            // 0..31 -> rows 2ti, 2ti+1
    const int tj = tid & 15;            // cols 4tj..4tj+3
    float4 qa0 = make_float4(0.f, 0.f, 0.f, 0.f);
    float4 qa1 = make_float4(0.f, 0.f, 0.f, 0.f);
    #pragma unroll 8
    for (int d = 0; d < 64; ++d) {
        float2 a2 = *(const float2*)&S1[d][2 * ti];
        float4 b4 = *(const float4*)&S2[d][4 * tj];
        qa0.x = fmaf(a2.x, b4.x, qa0.x);
        qa0.y = fmaf(a2.x, b4.y, qa0.y);
        qa0.z = fmaf(a2.x, b4.z, qa0.z);
        qa0.w = fmaf(a2.x, b4.w, qa0.w);
        qa1.x = fmaf(a2.y, b4.x, qa1.x);
        qa1.y = fmaf(a2.y, b4.y, qa1.y);
        qa1.z = fmaf(a2.y, b4.z, qa1.z);
        qa1.w = fmaf(a2.y, b4.w, qa1.w);
    }

    if (which == 0) {
        float* outp = eq + ((size_t)bh_i * 512 + t0) * 64;
        float4 o0, o1;
        o0.x = __builtin_amdgcn_exp2f(SCALE2 * qa0.x);
        o0.y = __builtin_amdgcn_exp2f(SCALE2 * qa0.y);
        o0.z = __builtin_amdgcn_exp2f(SCALE2 * qa0.z);
        o0.w = __builtin_amdgcn_exp2f(SCALE2 * qa0.w);
        o1.x = __builtin_amdgcn_exp2f(SCALE2 * qa1.x);
        o1.y = __builtin_amdgcn_exp2f(SCALE2 * qa1.y);
        o1.z = __builtin_amdgcn_exp2f(SCALE2 * qa1.z);
        o1.w = __builtin_amdgcn_exp2f(SCALE2 * qa1.w);
        *(float4*)&outp[(2 * ti + 0) * 64 + 4 * tj] = o0;
        *(float4*)&outp[(2 * ti + 1) * 64 + 4 * tj] = o1;
        return;
    }

    // which == 1: ekT (transposed, exp2'd, +b_h) and KhT (bf16 of C^T)
    float4 bhv = *(const float4*)&bh[h * 64 + 4 * tj];
    __syncthreads();
    S2[4 * tj + 0][2 * ti + 0] = __builtin_amdgcn_exp2f(SCALE2 * (qa0.x + bhv.x));
    S2[4 * tj + 0][2 * ti + 1] = __builtin_amdgcn_exp2f(SCALE2 * (qa1.x + bhv.x));
    S2[4 * tj + 1][2 * ti + 0] = __builtin_amdgcn_exp2f(SCALE2 * (qa0.y + bhv.y));
    S2[4 * tj + 1][2 * ti + 1] = __builtin_amdgcn_exp2f(SCALE2 * (qa1.y + bhv.y));
    S2[4 * tj + 2][2 * ti + 0] = __builtin_amdgcn_exp2f(SCALE2 * (qa0.z + bhv.z));
    S2[4 * tj + 2][2 * ti + 1] = __builtin_amdgcn_exp2f(SCALE2 * (qa1.z + bhv.z));
    S2[4 * tj + 3][2 * ti + 0] = __builtin_amdgcn_exp2f(SCALE2 * (qa0.w + bhv.w));
    S2[4 * tj + 3][2 * ti + 1] = __builtin_amdgcn_exp2f(SCALE2 * (qa1.w + bhv.w));
    __syncthreads();

    const int dd = tid >> 3;            // e (or d) 0..63
    const int sc = (tid & 7) * 8;       // s chunk
    float* ekp = ekT + ((size_t)bh_i * 64 + dd) * 512 + t0 + sc;
    *(float4*)&ekp[0] = *(float4*)&S2[dd][sc];
    *(float4*)&ekp[4] = *(float4*)&S2[dd][sc + 4];

    __hip_bfloat16* kp = KhT + ((size_t)bh_i * 64 + dd) * 512 + t0 + sc;
    union { short8 v; short s[8]; } pk;
    #pragma unroll
    for (int i = 0; i < 8; ++i) pk.s[i] = bfh(S1[dd][sc + i]);
    *(short8*)kp = pk.v;
}

// ============ additive-attention core v7: 4-way rational combine ============
// Old: per (t,e,s) one v_rcp (268M rcps/dispatch) -> trans-pipe roofline.
// New: sum 4 terms over a common denominator, ONE rcp per 4 elements:
//   u_i = 1 + eq_i*ek_i  (u>1, product of 4 bounded by ~6.5e20: fp32-safe)
//   N/D via 2-level combine, acc += N * rcp(D).
// rcp count 4x down (268M -> 67M); VALU ~15 ops/4e. Same math, fp32
// associativity change only. ek double-buffered in named 16-reg chunks.
__global__ __launch_bounds__(512, 4) void attn_v7(
    const float* __restrict__ eq, const float* __restrict__ ekT,
    const __hip_bfloat16* __restrict__ KhT, const float* __restrict__ va_h,
    float* __restrict__ merged)
{
    __shared__ __hip_bfloat16 pA[16][520];   // p in MFMA-A layout source, bf16
    __shared__ float wsum[16][8];

    const int tid = threadIdx.x;
    const int w = tid >> 6;
    const int l = tid & 63;
    const int bid = blockIdx.x;
    const int swz = (bid & 7) * 64 + (bid >> 3);   // bijective: 512 % 8 == 0
    const int t0 = (swz & 31) * 16;
    const int bh_i = swz >> 5;          // 0..15 = b*8 + h
    const int h = bh_i & 7;
    const int b = bh_i >> 3;

    const float* eq_p = eq + ((size_t)bh_i * 512 + t0) * 64;
    const float* ekT_p = ekT + (size_t)bh_i * 64 * 512 + tid;   // this thread's s
    const float* va_p = va_h + h * 64;

    float acc[16];
    #pragma unroll
    for (int t = 0; t < 16; ++t) acc[t] = 0.f;

    // process e in 4 chunks of 16, double-buffered in NAMED arrays (rule #20)
    float ekA[16], ekB[16];
    #pragma unroll
    for (int j = 0; j < 16; ++j) ekA[j] = ekT_p[j * 512];

#define SCORE_CHUNK(EKREG, E0)                                                  \
    {                                                                           \
        _Pragma("unroll")                                                       \
        for (int t = 0; t < 16; ++t) {                                          \
            float a = acc[t];                                                   \
            _Pragma("unroll")                                                   \
            for (int g = 0; g < 4; ++g) {                                       \
                float4 q4 = *(const float4*)&eq_p[t * 64 + (E0) + g * 4];       \
                float4 v4 = *(const float4*)&va_p[(E0) + g * 4];                \
                float u0 = fmaf(q4.x, EKREG[g * 4 + 0], 1.0f);                  \
                float u1 = fmaf(q4.y, EKREG[g * 4 + 1], 1.0f);                  \
                float u2 = fmaf(q4.z, EKREG[g * 4 + 2], 1.0f);                  \
                float u3 = fmaf(q4.w, EKREG[g * 4 + 3], 1.0f);                  \
                float d01 = u0 * u1;                                            \
                float n01 = fmaf(v4.x, u1, v4.y * u0);                          \
                float d23 = u2 * u3;                                            \
                float n23 = fmaf(v4.z, u3, v4.w * u2);                          \
                float D = d01 * d23;                                            \
                float N = fmaf(n01, d23, n23 * d01);                            \
                a = fmaf(N, __builtin_amdgcn_rcpf(D), a);                       \
            }                                                                   \
            acc[t] = a;                                                         \
        }                                                                       \
    }

    #pragma unroll
    for (int j = 0; j < 16; ++j) ekB[j] = ekT_p[(16 + j) * 512];
    SCORE_CHUNK(ekA, 0)
    #pragma unroll
    for (int j = 0; j < 16; ++j) ekA[j] = ekT_p[(32 + j) * 512];
    SCORE_CHUNK(ekB, 16)
    #pragma unroll
    for (int j = 0; j < 16; ++j) ekB[j] = ekT_p[(48 + j) * 512];
    SCORE_CHUNK(ekA, 32)
    SCORE_CHUNK(ekB, 48)
#undef SCORE_CHUNK

    // exp (no max-subtract; |score| bounded ~5) + per-t sum across 512 threads
    float ev[16];
    #pragma unroll
    for (int t = 0; t < 16; ++t) {
        float s = __builtin_amdgcn_exp2f(-SCALE2 * acc[t]);   // exp(-2*S_t)
        ev[t] = s;
        #pragma unroll
        for (int off = 32; off > 0; off >>= 1) s += __shfl_xor(s, off, 64);
        if (l == 0) wsum[t][w] = s;
    }
    __syncthreads();
    #pragma unroll
    for (int t = 0; t < 16; ++t) {
        float4 s0 = *(float4*)&wsum[t][0];
        float4 s1 = *(float4*)&wsum[t][4];
        float inv = 1.0f / (((s0.x + s0.y) + (s0.z + s0.w)) + ((s1.x + s1.y) + (s1.z + s1.w)));
        pA[t][tid] = __hip_bfloat16(ev[t] * inv);   // normalized p, bf16
    }
    __syncthreads();

    // P (16x512) @ K (512x64): 4 waves, wave w owns d-range [16w,16w+16)
    if (w < 4) {
        const __hip_bfloat16* kp = KhT + (size_t)bh_i * 64 * 512
                                   + ((size_t)(w * 16 + (l & 15))) * 512 + (l >> 4) * 8;
        const __hip_bfloat16* ap = &pA[l & 15][(l >> 4) * 8];
        floatx4 oacc = {0.f, 0.f, 0.f, 0.f};
        #pragma unroll
        for (int kt = 0; kt < 16; ++kt) {
            short8 af = *(const short8*)(ap + kt * 32);
            short8 bf = *(const short8*)(kp + kt * 32);
            oacc = __builtin_amdgcn_mfma_f32_16x16x32_bf16(af, bf, oacc, 0, 0, 0);
        }
        const int row = (l >> 4) * 4;        // t_local base
        const int col = w * 16 + (l & 15);   // d
        float* mp = merged + ((size_t)(b * 512 + t0 + row)) * 512 + h * 64 + col;
        #pragma unroll
        for (int r = 0; r < 4; ++r) mp[r * 512] = oacc[r];
    }
}

// ======= output projection (split-bf16 MFMA): C = A@Wo + bo =======
// UNCHANGED from verified R5 build.
__global__ __launch_bounds__(512) void gemm_out_mfma(
    const float* __restrict__ A, const float* __restrict__ W,
    const float* __restrict__ bias, float* __restrict__ C)
{
    __shared__ __align__(16) short BUF[192 * 72];
    short (*Ah)[72] = (short(*)[72])BUF;
    short (*Al)[72] = (short(*)[72])(BUF + 32 * 72);
    short (*Wh)[72] = (short(*)[72])(BUF + 64 * 72);
    short (*Wl)[72] = (short(*)[72])(BUF + 128 * 72);

    const int tid = threadIdx.x;
    const int n0 = blockIdx.x * 64;
    const int m0 = blockIdx.y * 32;
    const int wv = tid >> 6;
    const int l  = tid & 63;
    const int ms = (wv & 1) * 16;
    const int ns = (wv >> 1) * 16;
    const int fr = l & 15;
    const int fq = l >> 4;

    const int arow = tid >> 4;          // 0..31
    const int acol = (tid & 15) * 4;    // 0..60
    const int wn   = tid & 63;
    const int wkb  = (tid >> 6) * 8;

    const float bb = bias[n0 + ns + fr];
    floatx4 acc = {0.f, 0.f, 0.f, 0.f};

    float4 a0 = *(const float4*)&A[(m0 + arow) * 512 + acol];
    float wr[8];
    #pragma unroll
    for (int i = 0; i < 8; ++i) wr[i] = W[(wkb + i) * 512 + n0 + wn];

    for (int k0 = 0; k0 < 512; k0 += 64) {
        __syncthreads();
        {
            bshort4 h4, l4;
            split4(a0, h4, l4);
            *(bshort4*)&Ah[arow][acol] = h4;
            *(bshort4*)&Al[arow][acol] = l4;
            union { short8 v; short s[8]; } WH, WL;
            #pragma unroll
            for (int i = 0; i < 8; ++i) {
                short hh = bfh(wr[i]);
                WH.s[i] = hh;
                WL.s[i] = bfh(wr[i] - bff(hh));
            }
            *(short8*)&Wh[wn][wkb] = WH.v;
            *(short8*)&Wl[wn][wkb] = WL.v;
        }
        __syncthreads();
        if (k0 + 64 < 512) {
            a0 = *(const float4*)&A[(m0 + arow) * 512 + k0 + 64 + acol];
            #pragma unroll
            for (int i = 0; i < 8; ++i)
                wr[i] = W[(k0 + 64 + wkb + i) * 512 + n0 + wn];
        }
        #pragma unroll
        for (int kc = 0; kc < 2; ++kc) {
            const int ko = kc * 32 + fq * 8;
            short8 ah = *(const short8*)&Ah[ms + fr][ko];
            short8 al = *(const short8*)&Al[ms + fr][ko];
            short8 wh = *(const short8*)&Wh[ns + fr][ko];
            short8 wl = *(const short8*)&Wl[ns + fr][ko];
            acc = __builtin_amdgcn_mfma_f32_16x16x32_bf16(ah, wh, acc, 0, 0, 0);
            acc = __builtin_amdgcn_mfma_f32_16x16x32_bf16(ah, wl, acc, 0, 0, 0);
            acc = __builtin_amdgcn_mfma_f32_16x16x32_bf16(al, wh, acc, 0, 0, 0);
        }
    }

    const int mrow = m0 + ms + fq * 4;
    const int ncol = n0 + ns + fr;
    #pragma unroll
    for (int r = 0; r < 4; ++r)
        C[(size_t)(mrow + r) * 512 + ncol] = acc[r] + bb;
}

extern "C" void kernel_launch(void* const* d_in, const int* in_sizes, int n_in,
                              void* d_out, int out_size, void* d_ws, size_t ws_size,
                              hipStream_t stream) {
    (void)in_sizes; (void)n_in; (void)out_size; (void)ws_size;
    const float* query = (const float*)d_in[0];
    const float* key   = (const float*)d_in[1];
    // d_in[2] (value), d_in[7] (Wv), d_in[8] (bv): dead in the reference
    const float* Wq   = (const float*)d_in[3];
    const float* bq   = (const float*)d_in[4];
    const float* Wk   = (const float*)d_in[5];
    const float* bk   = (const float*)d_in[6];
    const float* Wq_h = (const float*)d_in[9];
    const float* Wk_h = (const float*)d_in[10];
    const float* va_h = (const float*)d_in[11];
    const float* b_h  = (const float*)d_in[12];
    const float* Wo   = (const float*)d_in[13];
    const float* bo   = (const float*)d_in[14];

    float* out = (float*)d_out;
    float* ws = (float*)d_ws;
    const int SZ = 1024 * 512;        // 524288 floats
    float* eqb     = ws;
    float* ekTb    = eqb + SZ;
    float* mergedb = ekTb + SZ;
    __hip_bfloat16* KhTb = (__hip_bfloat16*)(mergedb + SZ);   // 524288 bf16

    // fused: {Q,K} = In@W+b (split-bf16 MFMA), per-head transform -> eq/ekT/KhT
    qk_head_mfma<<<dim3(8, 16, 2), 512, 0, stream>>>(query, key, Wq, bq, Wk, bk,
                                                     Wq_h, Wk_h, b_h,
                                                     eqb, ekTb, KhTb);
    // scores (4-way rational) -> softmax -> P@K (MFMA); 512 blocks, XCD-swizzled
    attn_v7<<<dim3(512, 1, 1), 512, 0, stream>>>(eqb, ekTb, KhTb, va_h, mergedb);
    // out = merged@Wo + bo (split-bf16 MFMA, 256 blocks)
    gemm_out_mfma<<<dim3(8, 32, 1), 512, 0, stream>>>(mergedb, Wo, bo, out);
}